// Round 7
// baseline (1480.742 us; speedup 1.0000x reference)
//
#include <hip/hip_runtime.h>
#include <math.h>

typedef __bf16 bf16;
typedef __bf16 bf16x8 __attribute__((ext_vector_type(8)));
typedef float f32x4 __attribute__((ext_vector_type(4)));

#define DEVI static __device__ __forceinline__

DEVI float b2f(bf16 x){ return (float)x; }
DEVI bf16  f2b(float x){ return (bf16)x; }
DEVI float siluf_(float x){ return x / (1.f + __expf(-x)); }

DEVI void gload_lds16(const void* g, void* l){
  __builtin_amdgcn_global_load_lds((const __attribute__((address_space(1))) void*)g,
                                   (__attribute__((address_space(3))) void*)l, 16, 0, 0);
}

#define MFMA_  __builtin_amdgcn_mfma_f32_16x16x32_bf16

// ---------------------------------------------------------------------------
// gemm128s: C = A * W^T. m97 structure: 128x128 tile, BK=64, 4 waves (2x2),
// single-buffer LDS (32KB -> ~3 blocks/CU, implicit cross-block overlap),
// global_load_lds staging, plain __syncthreads. Plus: both-sides chunk-XOR
// LDS swizzle (0 bank conflicts, verified r4-r6) and bx-banded XCD remap
// (16 bx-tiles * 256KB = 4MB A per XCD = L2-resident, verified r6).
// Requires gridDim.x==128, M%128==0, N%128==0, K%64==0.
// Epilogues: 0 bf16 | 3 fp32 acc+aux[idx] | 4 C=silu(C)*acc bf16 | 5 C+=acc fp32
// ---------------------------------------------------------------------------
template<int EPI>
__global__ __launch_bounds__(256)
void gemm128s(const bf16* __restrict__ A, int lda,
              const bf16* __restrict__ W, int ldw,
              void* __restrict__ Cp, int ldc,
              const float* __restrict__ aux, int K)
{
  __shared__ __align__(16) bf16 As[128*64];
  __shared__ __align__(16) bf16 Bs[128*64];
  const int tid  = threadIdx.x;
  const int lane = tid & 63;
  const int wid  = tid >> 6;

  // bx-banded XCD remap: XCD k owns bx in [16k,16k+16), by-major inside.
  const int old = blockIdx.y*128 + blockIdx.x;
  const int bx = ((old & 7) << 4) | ((old >> 3) & 15);
  const int by = old >> 7;

  // staging: 4 gload_lds calls each for A and B; 16B chunk source-swizzled
  const bf16* aR[4]; const bf16* bR[4]; int dst[4];
#pragma unroll
  for (int l=0;l<4;l++){
    const int ci = l*256 + tid;          // chunk id 0..1023
    const int r  = ci >> 3;              // row 0..127
    const int ch = (ci & 7) ^ (r & 7);   // swizzled 16B chunk
    aR[l] = A + (long)(bx*128 + r)*lda + ch*8;
    bR[l] = W + (long)(by*128 + r)*ldw + ch*8;
    dst[l] = ci*8;
  }

  f32x4 acc[4][4];
#pragma unroll
  for (int i2=0;i2<4;i2++)
#pragma unroll
    for (int j2=0;j2<4;j2++) acc[i2][j2] = {0.f,0.f,0.f,0.f};

  const int wr = (wid>>1)<<6;
  const int wc = (wid&1)<<6;
  const int fr = lane & 15;
  const int fq = lane >> 4;
  const int rs = fr & 7;
  const int jsw0 = ((fq  ) ^ rs) << 3;   // kk=0 swizzled element offset
  const int jsw1 = ((4|fq) ^ rs) << 3;   // kk=1

  for (int k0=0; k0<K; k0+=64){
    __syncthreads();
#pragma unroll
    for (int l=0;l<4;l++){
      gload_lds16(aR[l] + k0, &As[dst[l]]);
      gload_lds16(bR[l] + k0, &Bs[dst[l]]);
    }
    __syncthreads();
    bf16x8 av0[4], av1[4], bv0[4], bv1[4];
#pragma unroll
    for (int mi=0; mi<4; mi++){
      av0[mi] = *(const bf16x8*)&As[(wr + mi*16 + fr)*64 + jsw0];
      av1[mi] = *(const bf16x8*)&As[(wr + mi*16 + fr)*64 + jsw1];
    }
#pragma unroll
    for (int nj=0; nj<4; nj++){
      bv0[nj] = *(const bf16x8*)&Bs[(wc + nj*16 + fr)*64 + jsw0];
      bv1[nj] = *(const bf16x8*)&Bs[(wc + nj*16 + fr)*64 + jsw1];
    }
#pragma unroll
    for (int mi=0; mi<4; mi++)
#pragma unroll
      for (int nj=0; nj<4; nj++){
        acc[mi][nj] = MFMA_(av0[mi], bv0[nj], acc[mi][nj], 0, 0, 0);
        acc[mi][nj] = MFMA_(av1[mi], bv1[nj], acc[mi][nj], 0, 0, 0);
      }
  }

  const int row0 = (bx<<7) + wr + (fq<<2);
  const int col0 = (by<<7) + wc + fr;
#pragma unroll
  for (int mi=0; mi<4; mi++){
#pragma unroll
    for (int nj=0; nj<4; nj++){
#pragma unroll
      for (int r=0; r<4; r++){
        const int row = row0 + mi*16 + r;
        const int col = col0 + nj*16;
        const long idx = (long)row*ldc + col;
        const float v = acc[mi][nj][r];
        if constexpr (EPI==0){ ((bf16*)Cp)[idx] = f2b(v); }
        else if constexpr (EPI==3){ ((float*)Cp)[idx] = v + aux[idx]; }
        else if constexpr (EPI==4){
          bf16* g = (bf16*)Cp;
          g[idx] = f2b(siluf_(b2f(g[idx])) * v);
        }
        else { float* o = (float*)Cp; o[idx] += v; }
      }
    }
  }
}

// ---------------------------------------------------------------------------
// legacy 128x128 GEMM (x_proj N=128, dt_proj K=64).
// EPI: 1 fp32 | 2 softplus(acc+aux[col])->bf16
// ---------------------------------------------------------------------------
template<int EPI>
__global__ __launch_bounds__(256)
void gemm_bt(const bf16* __restrict__ A, int lda,
             const bf16* __restrict__ W, int ldw,
             void* __restrict__ Cp, int ldc,
             const float* __restrict__ aux, int K)
{
  __shared__ __align__(16) bf16 As[128*64];
  __shared__ __align__(16) bf16 Bs[128*64];
  const int tid  = threadIdx.x;
  const int lane = tid & 63;
  const int wid  = tid >> 6;
  const int srow = tid >> 3;
  const int scol = (tid & 7) << 3;

  const bf16* Ag = A + (long)blockIdx.x*128*lda + (long)srow*lda + scol;
  const bf16* Wg = W + (long)blockIdx.y*128*ldw + (long)srow*ldw + scol;
  bf16* Asd = &As[tid*8];
  bf16* Bsd = &Bs[tid*8];

  f32x4 acc[4][4];
#pragma unroll
  for (int i2=0;i2<4;i2++)
#pragma unroll
    for (int j2=0;j2<4;j2++) acc[i2][j2] = {0.f,0.f,0.f,0.f};

  const int wr = (wid>>1)<<6;
  const int wc = (wid&1)<<6;
  const int fr = lane & 15;
  const int fq = lane >> 4;

  for (int k0=0; k0<K; k0+=64){
    __syncthreads();
#pragma unroll
    for (int is=0; is<4; is++){
      gload_lds16(Ag + (long)is*32*lda + k0, Asd + is*2048);
      gload_lds16(Wg + (long)is*32*ldw + k0, Bsd + is*2048);
    }
    __syncthreads();
#pragma unroll
    for (int kk=0; kk<2; kk++){
      bf16x8 av[4], bv[4];
#pragma unroll
      for (int mi=0; mi<4; mi++)
        av[mi] = *(const bf16x8*)&As[(wr + mi*16 + fr)*64 + kk*32 + fq*8];
#pragma unroll
      for (int nj=0; nj<4; nj++)
        bv[nj] = *(const bf16x8*)&Bs[(wc + nj*16 + fr)*64 + kk*32 + fq*8];
#pragma unroll
      for (int mi=0; mi<4; mi++)
#pragma unroll
        for (int nj=0; nj<4; nj++)
          acc[mi][nj] = MFMA_(av[mi], bv[nj], acc[mi][nj], 0, 0, 0);
    }
  }

  const int row0 = (blockIdx.x<<7) + wr + (fq<<2);
  const int col0 = (blockIdx.y<<7) + wc + fr;
#pragma unroll
  for (int mi=0; mi<4; mi++){
#pragma unroll
    for (int nj=0; nj<4; nj++){
#pragma unroll
      for (int r=0; r<4; r++){
        const int row = row0 + mi*16 + r;
        const int col = col0 + nj*16;
        const long idx = (long)row*ldc + col;
        const float v = acc[mi][nj][r];
        if constexpr (EPI==1){ ((float*)Cp)[idx] = v; }
        else if constexpr (EPI==2){
          float t = v + aux[col];
          ((bf16*)Cp)[idx] = f2b(t > 20.f ? t : log1pf(__expf(t)));
        }
        else { ((bf16*)Cp)[idx] = f2b(v); }
      }
    }
  }
}

__global__ void k_convert(const float* __restrict__ src, bf16* __restrict__ dst,
                          int n_dst, int n_src){
  int i = blockIdx.x*256 + threadIdx.x;
  if (i < n_dst) dst[i] = (i < n_src) ? f2b(src[i]) : f2b(0.f);
}

// RMSNorm over rows of 1024 fp32 -> bf16
__global__ __launch_bounds__(256)
void k_rmsnorm(const float* __restrict__ x, const float* __restrict__ w,
               bf16* __restrict__ out){
  const int row = blockIdx.x;
  const float4 v = ((const float4*)(x + (long)row*1024))[threadIdx.x];
  float ss = v.x*v.x + v.y*v.y + v.z*v.z + v.w*v.w;
#pragma unroll
  for (int off=32; off; off>>=1) ss += __shfl_down(ss, off);
  __shared__ float ps[4];
  if ((threadIdx.x & 63) == 0) ps[threadIdx.x>>6] = ss;
  __syncthreads();
  const float tot = ps[0]+ps[1]+ps[2]+ps[3];
  const float scale = rsqrtf(tot*(1.f/1024.f) + 1e-5f);
  const float4 wv = ((const float4*)w)[threadIdx.x];
  bf16* o = out + (long)row*1024 + threadIdx.x*4;
  o[0]=f2b(v.x*scale*wv.x); o[1]=f2b(v.y*scale*wv.y);
  o[2]=f2b(v.z*scale*wv.z); o[3]=f2b(v.w*scale*wv.w);
}

// vectorized causal depthwise conv (K=4) + bias + SiLU: thread = 8 channels
__global__ __launch_bounds__(256)
void k_conv8(const bf16* __restrict__ xiraw, const float* __restrict__ cw,
             const float* __restrict__ cb, bf16* __restrict__ out){
  const long gid = (long)blockIdx.x*256 + threadIdx.x;   // BT * 256 octets
  const int c8 = (int)(gid & 255);
  const long rowg = gid >> 8;
  const int t = (int)(rowg & 2047);
  const int ch = c8 << 3;

  const float4* cwp = (const float4*)(cw + ch*4);  // taps for 8 channels
  float4 cb0 = ((const float4*)(cb + ch))[0];
  float4 cb1 = ((const float4*)(cb + ch))[1];
  float acc[8] = {cb0.x,cb0.y,cb0.z,cb0.w,cb1.x,cb1.y,cb1.z,cb1.w};

#pragma unroll
  for (int k=0;k<4;k++){
    const int tt = t + k - 3;
    if (tt >= 0){
      const bf16x8 v = *(const bf16x8*)&xiraw[(rowg + k - 3)*2048 + ch];
#pragma unroll
      for (int j=0;j<8;j++){
        const float wkt = ((const float*)&cwp[j])[k];
        acc[j] = fmaf(b2f(v[j]), wkt, acc[j]);
      }
    }
  }
  bf16x8 o;
#pragma unroll
  for (int j=0;j<8;j++) o[j] = f2b(siluf_(acc[j]));
  *(bf16x8*)&out[rowg*2048 + ch] = o;
}

// sp[:, 0:64] fp32 -> bf16
__global__ void k_dtr(const float* __restrict__ sp, bf16* __restrict__ dtr){
  int idx = blockIdx.x*256 + threadIdx.x;
  dtr[idx] = f2b(sp[(long)(idx>>6)*128 + (idx&63)]);
}

// -------------------- chunked parallel scan (C=16, L=128) ------------------
#define NCHUNK 16
#define CLEN   128

__global__ __launch_bounds__(64)
void k_scanA(const bf16* __restrict__ dt, const bf16* __restrict__ xi,
             const float* __restrict__ sp, const float* __restrict__ A_log,
             float* __restrict__ F, float* __restrict__ SDT)
{
  const int tid = threadIdx.x;
  const int blk = blockIdx.x;
  const int c = blk & 15;
  const int g = (blk >> 4) & 31;
  const int b = blk >> 9;
  const int i = (g << 6) + tid;
  float Ar[16], s[16];
#pragma unroll
  for (int n=0;n<16;n++){ Ar[n] = -__expf(A_log[i*16+n]); s[n]=0.f; }
  float sdt = 0.f;
  __shared__ float Bsm[64][16];
  for (int tc=0; tc<CLEN/64; tc++){
    const int rowbase = b*2048 + c*CLEN + tc*64;
    __syncthreads();
#pragma unroll
    for (int j=0;j<16;j++){
      const int idx = (j<<6) + tid;
      Bsm[idx>>4][idx&15] = sp[(long)(rowbase + (idx>>4))*128 + 64 + (idx&15)];
    }
    __syncthreads();
    for (int tt=0; tt<64; tt+=4){
      float dtv[4], xv[4];
#pragma unroll
      for (int j2=0;j2<4;j2++){
        const long gg = (long)(rowbase+tt+j2)*2048 + i;
        dtv[j2] = b2f(dt[gg]); xv[j2] = b2f(xi[gg]);
      }
#pragma unroll
      for (int j2=0;j2<4;j2++){
        sdt += dtv[j2];
        const float dx = dtv[j2]*xv[j2];
#pragma unroll
        for (int n=0;n<16;n++)
          s[n] = fmaf(__expf(dtv[j2]*Ar[n]), s[n], dx*Bsm[tt+j2][n]);
      }
    }
  }
#pragma unroll
  for (int n=0;n<16;n++) F[((long)blk*16 + n)*64 + tid] = s[n];
  SDT[(long)blk*64 + tid] = sdt;
}

__global__ __launch_bounds__(256)
void k_scanB(float* __restrict__ F, const float* __restrict__ SDT,
             const float* __restrict__ A_log)
{
  const int t = blockIdx.x*256 + threadIdx.x;
  const int lane = t & 63;
  const int n = (t >> 6) & 15;
  const int g = (t >> 10) & 31;
  const int b = t >> 15;
  const int i = (g << 6) + lane;
  const float Ar = -__expf(A_log[i*16+n]);
  const long base = ((long)(b*32+g))*NCHUNK;
  float s0 = 0.f;
#pragma unroll
  for (int c=0;c<NCHUNK;c++){
    const long fidx = ((base + c)*16 + n)*64 + lane;
    const float f = F[fidx];
    const float p = __expf(Ar * SDT[(base + c)*64 + lane]);
    F[fidx] = s0;
    s0 = f + p*s0;
  }
}

__global__ __launch_bounds__(64)
void k_scanC(const bf16* __restrict__ dt, bf16* __restrict__ xiy,
             const float* __restrict__ sp, const float* __restrict__ A_log,
             const bf16* __restrict__ gate, const float* __restrict__ Dw,
             const float* __restrict__ S0)
{
  const int tid = threadIdx.x;
  const int blk = blockIdx.x;
  const int c = blk & 15;
  const int g = (blk >> 4) & 31;
  const int b = blk >> 9;
  const int i = (g << 6) + tid;
  const float Di = Dw[i];
  float Ar[16], s[16];
#pragma unroll
  for (int n=0;n<16;n++){
    Ar[n] = -__expf(A_log[i*16+n]);
    s[n] = S0[((long)blk*16 + n)*64 + tid];
  }
  __shared__ float BCs[64][32];
  for (int tc=0; tc<CLEN/64; tc++){
    const int rowbase = b*2048 + c*CLEN + tc*64;
    __syncthreads();
#pragma unroll
    for (int j=0;j<32;j++){
      const int idx = (j<<6) + tid;
      BCs[idx>>5][idx&31] = sp[(long)(rowbase + (idx>>5))*128 + 64 + (idx&31)];
    }
    __syncthreads();
    for (int tt=0; tt<64; tt+=4){
      float dtv[4], xv[4], gv[4];
#pragma unroll
      for (int j2=0;j2<4;j2++){
        const long gg = (long)(rowbase+tt+j2)*2048 + i;
        dtv[j2] = b2f(dt[gg]); xv[j2] = b2f(xiy[gg]); gv[j2] = b2f(gate[gg]);
      }
#pragma unroll
      for (int j2=0;j2<4;j2++){
        const float dx = dtv[j2]*xv[j2];
        float yv = 0.f;
#pragma unroll
        for (int n=0;n<16;n++){
          s[n] = fmaf(__expf(dtv[j2]*Ar[n]), s[n], dx*BCs[tt+j2][n]);
          yv = fmaf(s[n], BCs[tt+j2][16+n], yv);
        }
        xiy[(long)(rowbase+tt+j2)*2048 + i] = f2b((yv + xv[j2]*Di) * siluf_(gv[j2]));
      }
    }
  }
}

extern "C" void kernel_launch(void* const* d_in, const int* in_sizes, int n_in,
                              void* d_out, int out_size, void* d_ws, size_t ws_size,
                              hipStream_t stream)
{
  const float* x         = (const float*)d_in[0];
  const float* mixer_w   = (const float*)d_in[1];
  const float* in_proj_w = (const float*)d_in[2];
  const float* conv_w    = (const float*)d_in[3];
  const float* conv_b    = (const float*)d_in[4];
  const float* x_proj_w  = (const float*)d_in[5];
  const float* dt_proj_w = (const float*)d_in[6];
  const float* dt_proj_b = (const float*)d_in[7];
  const float* A_log     = (const float*)d_in[8];
  const float* Dv        = (const float*)d_in[9];
  const float* out_proj_w= (const float*)d_in[10];
  const float* mlp_w     = (const float*)d_in[11];
  const float* gate_w    = (const float*)d_in[12];
  const float* up_w      = (const float*)d_in[13];
  const float* down_w    = (const float*)d_in[14];
  float* outp = (float*)d_out;

  char* p = (char*)d_ws;
  auto alloc = [&](size_t n){ char* r = p; p += (n + 255) & ~(size_t)255; return (void*)r; };
  bf16* wb_in   = (bf16*)alloc((size_t)4096*1024*2);
  bf16* wb_xp   = (bf16*)alloc((size_t)128*2048*2);
  bf16* wb_dt   = (bf16*)alloc((size_t)2048*64*2);
  bf16* wb_out  = (bf16*)alloc((size_t)1024*2048*2);
  bf16* wb_gate = (bf16*)alloc((size_t)2816*1024*2);
  bf16* wb_up   = (bf16*)alloc((size_t)2816*1024*2);
  bf16* wb_down = (bf16*)alloc((size_t)1024*2816*2);
  char* r1      = (char*)alloc((size_t)32<<20);
  char* r2      = (char*)alloc((size_t)64<<20);
  char* r3      = (char*)alloc((size_t)64<<20);
  char* r4      = (char*)alloc((size_t)64<<20);
  if ((size_t)(p - (char*)d_ws) > ws_size) return;

  bf16*  xb     = (bf16*)r1;
  float* sp     = (float*)r1;
  bf16*  dtr    = (bf16*)(r1 + (8<<20));
  float* Fbuf   = (float*)(r1 + (10<<20));
  float* SDT    = (float*)(r1 + (28<<20));
  bf16*  xiraw  = (bf16*)r2;
  bf16*  dtb    = (bf16*)r2;
  bf16*  gateb  = (bf16*)r3;
  bf16*  xiconv = (bf16*)r4;
  bf16*  gbuf   = (bf16*)r3;

  auto cv = [&](const float* s_, bf16* d_, int nd, int ns){
    k_convert<<<dim3((nd+255)/256), dim3(256), 0, stream>>>(s_, d_, nd, ns);
  };
  cv(in_proj_w,  wb_in,   4096*1024, 4096*1024);
  cv(x_proj_w,   wb_xp,   128*2048,  96*2048);
  cv(dt_proj_w,  wb_dt,   2048*64,   2048*64);
  cv(out_proj_w, wb_out,  1024*2048, 1024*2048);
  cv(gate_w,     wb_gate, 2816*1024, 2816*1024);
  cv(up_w,       wb_up,   2816*1024, 2816*1024);
  cv(down_w,     wb_down, 1024*2816, 1024*2816);

  // 1. h = rmsnorm(x)
  k_rmsnorm<<<16384, 256, 0, stream>>>(x, mixer_w, xb);
  // 2. xi / gate halves of in_proj (128^2 m97-structure + swizzle + banding)
  gemm128s<0><<<dim3(128,16), 256, 0, stream>>>(xb, 1024, wb_in,             1024, xiraw, 2048, nullptr, 1024);
  gemm128s<0><<<dim3(128,16), 256, 0, stream>>>(xb, 1024, wb_in + 2048*1024, 1024, gateb, 2048, nullptr, 1024);
  // 3. conv + silu (vectorized)
  k_conv8<<<16384, 256, 0, stream>>>(xiraw, conv_w, conv_b, xiconv);
  // 4. sp = xiconv @ x_proj^T (N=128 -> legacy kernel, fp32 out)
  gemm_bt<1><<<dim3(128,1), 256, 0, stream>>>(xiconv, 2048, wb_xp, 2048, sp, 128, nullptr, 2048);
  // 5. dt_r
  k_dtr<<<4096, 256, 0, stream>>>(sp, dtr);
  // 6. dt = softplus(dt_r @ dt_proj^T + b)  (K=64 -> legacy)
  gemm_bt<2><<<dim3(128,16), 256, 0, stream>>>(dtr, 64, wb_dt, 64, dtb, 2048, dt_proj_b, 64);
  // 7. chunked scan
  k_scanA<<<4096, 64, 0, stream>>>(dtb, xiconv, sp, A_log, Fbuf, SDT);
  k_scanB<<<1024, 256, 0, stream>>>(Fbuf, SDT, A_log);
  k_scanC<<<4096, 64, 0, stream>>>(dtb, xiconv, sp, A_log, gateb, Dv, Fbuf);
  // 8. x2 = x + y @ out_proj^T -> d_out
  gemm128s<3><<<dim3(128,8), 256, 0, stream>>>(xiconv, 2048, wb_out, 2048, outp, 1024, x, 2048);
  // 9. h2 = rmsnorm(x2)
  k_rmsnorm<<<16384, 256, 0, stream>>>(outp, mlp_w, xb);
  // 10. g = h2 @ gate^T
  gemm128s<0><<<dim3(128,22), 256, 0, stream>>>(xb, 1024, wb_gate, 1024, gbuf, 2816, nullptr, 1024);
  // 11. g = silu(g) * (h2 @ up^T)
  gemm128s<4><<<dim3(128,22), 256, 0, stream>>>(xb, 1024, wb_up, 1024, gbuf, 2816, nullptr, 1024);
  // 12. d_out += g @ down^T
  gemm128s<5><<<dim3(128,8), 256, 0, stream>>>(gbuf, 2816, wb_down, 2816, outp, 1024, nullptr, 2816);
}

// Round 8
// 1288.793 us; speedup vs baseline: 1.1489x; 1.1489x over previous
//
#include <hip/hip_runtime.h>
#include <math.h>

typedef __bf16 bf16;
typedef __bf16 bf16x8 __attribute__((ext_vector_type(8)));
typedef float f32x4 __attribute__((ext_vector_type(4)));

#define DEVI static __device__ __forceinline__

DEVI float b2f(bf16 x){ return (float)x; }
DEVI bf16  f2b(float x){ return (bf16)x; }
DEVI float siluf_(float x){ return x / (1.f + __expf(-x)); }

DEVI void gload_lds16(const void* g, void* l){
  __builtin_amdgcn_global_load_lds((const __attribute__((address_space(1))) void*)g,
                                   (__attribute__((address_space(3))) void*)l, 16, 0, 0);
}

#define MFMA_  __builtin_amdgcn_mfma_f32_16x16x32_bf16

// ---------------------------------------------------------------------------
// gemm128s: C = A * W^T. m97 structure (128x128, BK=64, 4 waves, single-buffer
// LDS, global_load_lds) + both-sides chunk-XOR swizzle (0 conflicts) +
// bx-banded XCD remap. Requires gridDim.x==128.
// Epilogues: 0 bf16 | 3 fp32 acc+aux[idx] | 5 C+=acc fp32
// ---------------------------------------------------------------------------
template<int EPI>
__global__ __launch_bounds__(256)
void gemm128s(const bf16* __restrict__ A, int lda,
              const bf16* __restrict__ W, int ldw,
              void* __restrict__ Cp, int ldc,
              const float* __restrict__ aux, int K)
{
  __shared__ __align__(16) bf16 As[128*64];
  __shared__ __align__(16) bf16 Bs[128*64];
  const int tid  = threadIdx.x;
  const int lane = tid & 63;
  const int wid  = tid >> 6;

  const int old = blockIdx.y*128 + blockIdx.x;
  const int bx = ((old & 7) << 4) | ((old >> 3) & 15);
  const int by = old >> 7;

  const bf16* aR[4]; const bf16* bR[4]; int dst[4];
#pragma unroll
  for (int l=0;l<4;l++){
    const int ci = l*256 + tid;
    const int r  = ci >> 3;
    const int ch = (ci & 7) ^ (r & 7);
    aR[l] = A + (long)(bx*128 + r)*lda + ch*8;
    bR[l] = W + (long)(by*128 + r)*ldw + ch*8;
    dst[l] = ci*8;
  }

  f32x4 acc[4][4];
#pragma unroll
  for (int i2=0;i2<4;i2++)
#pragma unroll
    for (int j2=0;j2<4;j2++) acc[i2][j2] = {0.f,0.f,0.f,0.f};

  const int wr = (wid>>1)<<6;
  const int wc = (wid&1)<<6;
  const int fr = lane & 15;
  const int fq = lane >> 4;
  const int rs = fr & 7;
  const int jsw0 = ((fq  ) ^ rs) << 3;
  const int jsw1 = ((4|fq) ^ rs) << 3;

  for (int k0=0; k0<K; k0+=64){
    __syncthreads();
#pragma unroll
    for (int l=0;l<4;l++){
      gload_lds16(aR[l] + k0, &As[dst[l]]);
      gload_lds16(bR[l] + k0, &Bs[dst[l]]);
    }
    __syncthreads();
    bf16x8 av0[4], av1[4], bv0[4], bv1[4];
#pragma unroll
    for (int mi=0; mi<4; mi++){
      av0[mi] = *(const bf16x8*)&As[(wr + mi*16 + fr)*64 + jsw0];
      av1[mi] = *(const bf16x8*)&As[(wr + mi*16 + fr)*64 + jsw1];
    }
#pragma unroll
    for (int nj=0; nj<4; nj++){
      bv0[nj] = *(const bf16x8*)&Bs[(wc + nj*16 + fr)*64 + jsw0];
      bv1[nj] = *(const bf16x8*)&Bs[(wc + nj*16 + fr)*64 + jsw1];
    }
#pragma unroll
    for (int mi=0; mi<4; mi++)
#pragma unroll
      for (int nj=0; nj<4; nj++){
        acc[mi][nj] = MFMA_(av0[mi], bv0[nj], acc[mi][nj], 0, 0, 0);
        acc[mi][nj] = MFMA_(av1[mi], bv1[nj], acc[mi][nj], 0, 0, 0);
      }
  }

  const int row0 = (bx<<7) + wr + (fq<<2);
  const int col0 = (by<<7) + wc + fr;
#pragma unroll
  for (int mi=0; mi<4; mi++){
#pragma unroll
    for (int nj=0; nj<4; nj++){
#pragma unroll
      for (int r=0; r<4; r++){
        const int row = row0 + mi*16 + r;
        const int col = col0 + nj*16;
        const long idx = (long)row*ldc + col;
        const float v = acc[mi][nj][r];
        if constexpr (EPI==0){ ((bf16*)Cp)[idx] = f2b(v); }
        else if constexpr (EPI==3){ ((float*)Cp)[idx] = v + aux[idx]; }
        else { float* o = (float*)Cp; o[idx] += v; }
      }
    }
  }
}

// ---------------------------------------------------------------------------
// gemm_fused: gate/up fused MLP front. W = wb_gu (5632x1024, 64-row interleave:
// chunk c rows [c*128, c*128+64) = gate rows [c*64..), [c*128+64, c*128+128) =
// up rows [c*64..)). Block: A-tile 128 rows x B-tile 128 rows (= 64 gate cols
// + 64 up cols of the SAME output range). Gate waves (wc=0) pass fp32 tile via
// LDS; up waves (wc=64) write silu(g)*u bf16 to Cp cols [by*64, by*64+64).
// Grid dim3(128, 44).
// ---------------------------------------------------------------------------
__global__ __launch_bounds__(256)
void gemm_fused(const bf16* __restrict__ A, int lda,
                const bf16* __restrict__ W, int ldw,
                bf16* __restrict__ Cp, int ldc, int K)
{
  __shared__ __align__(16) bf16 As[128*64];
  __shared__ __align__(16) bf16 Bs[128*64];
  const int tid  = threadIdx.x;
  const int lane = tid & 63;
  const int wid  = tid >> 6;

  const int old = blockIdx.y*128 + blockIdx.x;
  const int bx = ((old & 7) << 4) | ((old >> 3) & 15);
  const int by = old >> 7;

  const bf16* aR[4]; const bf16* bR[4]; int dst[4];
#pragma unroll
  for (int l=0;l<4;l++){
    const int ci = l*256 + tid;
    const int r  = ci >> 3;
    const int ch = (ci & 7) ^ (r & 7);
    aR[l] = A + (long)(bx*128 + r)*lda + ch*8;
    bR[l] = W + (long)(by*128 + r)*ldw + ch*8;
    dst[l] = ci*8;
  }

  f32x4 acc[4][4];
#pragma unroll
  for (int i2=0;i2<4;i2++)
#pragma unroll
    for (int j2=0;j2<4;j2++) acc[i2][j2] = {0.f,0.f,0.f,0.f};

  const int wr = (wid>>1)<<6;
  const int wc = (wid&1)<<6;     // 0 = gate half, 64 = up half
  const int fr = lane & 15;
  const int fq = lane >> 4;
  const int rs = fr & 7;
  const int jsw0 = ((fq  ) ^ rs) << 3;
  const int jsw1 = ((4|fq) ^ rs) << 3;

  for (int k0=0; k0<K; k0+=64){
    __syncthreads();
#pragma unroll
    for (int l=0;l<4;l++){
      gload_lds16(aR[l] + k0, &As[dst[l]]);
      gload_lds16(bR[l] + k0, &Bs[dst[l]]);
    }
    __syncthreads();
    bf16x8 av0[4], av1[4], bv0[4], bv1[4];
#pragma unroll
    for (int mi=0; mi<4; mi++){
      av0[mi] = *(const bf16x8*)&As[(wr + mi*16 + fr)*64 + jsw0];
      av1[mi] = *(const bf16x8*)&As[(wr + mi*16 + fr)*64 + jsw1];
    }
#pragma unroll
    for (int nj=0; nj<4; nj++){
      bv0[nj] = *(const bf16x8*)&Bs[(wc + nj*16 + fr)*64 + jsw0];
      bv1[nj] = *(const bf16x8*)&Bs[(wc + nj*16 + fr)*64 + jsw1];
    }
#pragma unroll
    for (int mi=0; mi<4; mi++)
#pragma unroll
      for (int nj=0; nj<4; nj++){
        acc[mi][nj] = MFMA_(av0[mi], bv0[nj], acc[mi][nj], 0, 0, 0);
        acc[mi][nj] = MFMA_(av1[mi], bv1[nj], acc[mi][nj], 0, 0, 0);
      }
  }

  // epilogue: gate tile -> LDS (fp32), up waves combine
  __syncthreads();                       // all waves done reading As/Bs
  float* Gf = (wr == 0) ? (float*)As : (float*)Bs;   // 64x64 fp32 each
  if (wc == 0){
#pragma unroll
    for (int mi=0; mi<4; mi++)
#pragma unroll
      for (int nj=0; nj<4; nj++)
#pragma unroll
        for (int r=0; r<4; r++){
          const int rl = mi*16 + (fq<<2) + r;
          const int cl = nj*16 + fr;
          Gf[rl*64 + cl] = acc[mi][nj][r];
        }
  }
  __syncthreads();
  if (wc == 64){
#pragma unroll
    for (int mi=0; mi<4; mi++)
#pragma unroll
      for (int nj=0; nj<4; nj++)
#pragma unroll
        for (int r=0; r<4; r++){
          const int rl = mi*16 + (fq<<2) + r;
          const int cl = nj*16 + fr;
          const float g = Gf[rl*64 + cl];
          const int row = (bx<<7) + wr + rl;
          const int col = by*64 + cl;
          Cp[(long)row*ldc + col] = f2b(siluf_(g) * acc[mi][nj][r]);
        }
  }
}

// ---------------------------------------------------------------------------
// gemm_xp: x_proj. A (BT x 2048) bf16, W = wb_xp (128 x 2048) bf16.
// Tile 64x128, 4 waves (2Mx2N), K=2048. Writes sp fp32 [row][128] and
// dtr bf16 [row][64] (cols<64) in epilogue. Grid dim3(256,1).
// ---------------------------------------------------------------------------
__global__ __launch_bounds__(256)
void gemm_xp(const bf16* __restrict__ A, const bf16* __restrict__ W,
             float* __restrict__ sp, bf16* __restrict__ dtr, int K)
{
  __shared__ __align__(16) bf16 As[64*64];
  __shared__ __align__(16) bf16 Bs[128*64];
  const int tid  = threadIdx.x;
  const int lane = tid & 63;
  const int wid  = tid >> 6;
  const int bx = blockIdx.x;

  const bf16* aR[2]; int dstA[2];
#pragma unroll
  for (int l=0;l<2;l++){
    const int ci = l*256 + tid;          // 0..511
    const int r  = ci >> 3;              // 0..63
    const int ch = (ci & 7) ^ (r & 7);
    aR[l] = A + (long)(bx*64 + r)*2048 + ch*8;
    dstA[l] = ci*8;
  }
  const bf16* bR[4]; int dstB[4];
#pragma unroll
  for (int l=0;l<4;l++){
    const int ci = l*256 + tid;
    const int r  = ci >> 3;
    const int ch = (ci & 7) ^ (r & 7);
    bR[l] = W + (long)r*2048 + ch*8;
    dstB[l] = ci*8;
  }

  f32x4 acc[2][4];
#pragma unroll
  for (int i2=0;i2<2;i2++)
#pragma unroll
    for (int j2=0;j2<4;j2++) acc[i2][j2] = {0.f,0.f,0.f,0.f};

  const int wr = (wid>>1)<<5;
  const int wc = (wid&1)<<6;
  const int fr = lane & 15;
  const int fq = lane >> 4;
  const int rs = fr & 7;
  const int jsw0 = ((fq  ) ^ rs) << 3;
  const int jsw1 = ((4|fq) ^ rs) << 3;

  for (int k0=0; k0<K; k0+=64){
    __syncthreads();
#pragma unroll
    for (int l=0;l<2;l++) gload_lds16(aR[l] + k0, &As[dstA[l]]);
#pragma unroll
    for (int l=0;l<4;l++) gload_lds16(bR[l] + k0, &Bs[dstB[l]]);
    __syncthreads();
    bf16x8 av0[2], av1[2], bv0[4], bv1[4];
#pragma unroll
    for (int mi=0; mi<2; mi++){
      av0[mi] = *(const bf16x8*)&As[(wr + mi*16 + fr)*64 + jsw0];
      av1[mi] = *(const bf16x8*)&As[(wr + mi*16 + fr)*64 + jsw1];
    }
#pragma unroll
    for (int nj=0; nj<4; nj++){
      bv0[nj] = *(const bf16x8*)&Bs[(wc + nj*16 + fr)*64 + jsw0];
      bv1[nj] = *(const bf16x8*)&Bs[(wc + nj*16 + fr)*64 + jsw1];
    }
#pragma unroll
    for (int mi=0; mi<2; mi++)
#pragma unroll
      for (int nj=0; nj<4; nj++){
        acc[mi][nj] = MFMA_(av0[mi], bv0[nj], acc[mi][nj], 0, 0, 0);
        acc[mi][nj] = MFMA_(av1[mi], bv1[nj], acc[mi][nj], 0, 0, 0);
      }
  }

  const int row0 = (bx<<6) + wr + (fq<<2);
  const int col0 = wc + fr;
#pragma unroll
  for (int mi=0; mi<2; mi++){
#pragma unroll
    for (int nj=0; nj<4; nj++){
#pragma unroll
      for (int r=0; r<4; r++){
        const int row = row0 + mi*16 + r;
        const int col = col0 + nj*16;
        const float v = acc[mi][nj][r];
        sp[(long)row*128 + col] = v;
        if (col < 64) dtr[(long)row*64 + col] = f2b(v);
      }
    }
  }
}

// ---------------------------------------------------------------------------
// legacy 128x128 GEMM (dt_proj K=64). EPI 2: softplus(acc+aux[col])->bf16
// ---------------------------------------------------------------------------
template<int EPI>
__global__ __launch_bounds__(256)
void gemm_bt(const bf16* __restrict__ A, int lda,
             const bf16* __restrict__ W, int ldw,
             void* __restrict__ Cp, int ldc,
             const float* __restrict__ aux, int K)
{
  __shared__ __align__(16) bf16 As[128*64];
  __shared__ __align__(16) bf16 Bs[128*64];
  const int tid  = threadIdx.x;
  const int lane = tid & 63;
  const int wid  = tid >> 6;
  const int srow = tid >> 3;
  const int scol = (tid & 7) << 3;

  const bf16* Ag = A + (long)blockIdx.x*128*lda + (long)srow*lda + scol;
  const bf16* Wg = W + (long)blockIdx.y*128*ldw + (long)srow*ldw + scol;
  bf16* Asd = &As[tid*8];
  bf16* Bsd = &Bs[tid*8];

  f32x4 acc[4][4];
#pragma unroll
  for (int i2=0;i2<4;i2++)
#pragma unroll
    for (int j2=0;j2<4;j2++) acc[i2][j2] = {0.f,0.f,0.f,0.f};

  const int wr = (wid>>1)<<6;
  const int wc = (wid&1)<<6;
  const int fr = lane & 15;
  const int fq = lane >> 4;

  for (int k0=0; k0<K; k0+=64){
    __syncthreads();
#pragma unroll
    for (int is=0; is<4; is++){
      gload_lds16(Ag + (long)is*32*lda + k0, Asd + is*2048);
      gload_lds16(Wg + (long)is*32*ldw + k0, Bsd + is*2048);
    }
    __syncthreads();
#pragma unroll
    for (int kk=0; kk<2; kk++){
      bf16x8 av[4], bv[4];
#pragma unroll
      for (int mi=0; mi<4; mi++)
        av[mi] = *(const bf16x8*)&As[(wr + mi*16 + fr)*64 + kk*32 + fq*8];
#pragma unroll
      for (int nj=0; nj<4; nj++)
        bv[nj] = *(const bf16x8*)&Bs[(wc + nj*16 + fr)*64 + kk*32 + fq*8];
#pragma unroll
      for (int mi=0; mi<4; mi++)
#pragma unroll
        for (int nj=0; nj<4; nj++)
          acc[mi][nj] = MFMA_(av[mi], bv[nj], acc[mi][nj], 0, 0, 0);
    }
  }

  const int row0 = (blockIdx.x<<7) + wr + (fq<<2);
  const int col0 = (blockIdx.y<<7) + wc + fr;
#pragma unroll
  for (int mi=0; mi<4; mi++){
#pragma unroll
    for (int nj=0; nj<4; nj++){
#pragma unroll
      for (int r=0; r<4; r++){
        const int row = row0 + mi*16 + r;
        const int col = col0 + nj*16;
        const long idx = (long)row*ldc + col;
        const float v = acc[mi][nj][r];
        if constexpr (EPI==2){
          float t = v + aux[col];
          ((bf16*)Cp)[idx] = f2b(t > 20.f ? t : log1pf(__expf(t)));
        }
        else { ((bf16*)Cp)[idx] = f2b(v); }
      }
    }
  }
}

__global__ void k_convert(const float* __restrict__ src, bf16* __restrict__ dst,
                          int n_dst, int n_src){
  int i = blockIdx.x*256 + threadIdx.x;
  if (i < n_dst) dst[i] = (i < n_src) ? f2b(src[i]) : f2b(0.f);
}

// interleaved gate/up convert: chunk c rows [0..64)=gate[c*64..], [64..128)=up
__global__ void k_conv_gu(const float* __restrict__ g, const float* __restrict__ u,
                          bf16* __restrict__ dst){
  const long i = (long)blockIdx.x*256 + threadIdx.x;   // 5632*1024
  const int row = (int)(i >> 10), col = (int)(i & 1023);
  const int chunk = row >> 7, j = row & 127;
  const float* s = (j < 64) ? (g + (long)(chunk*64 + j)*1024 + col)
                            : (u + (long)(chunk*64 + j - 64)*1024 + col);
  dst[i] = f2b(*s);
}

// RMSNorm over rows of 1024 fp32 -> bf16
__global__ __launch_bounds__(256)
void k_rmsnorm(const float* __restrict__ x, const float* __restrict__ w,
               bf16* __restrict__ out){
  const int row = blockIdx.x;
  const float4 v = ((const float4*)(x + (long)row*1024))[threadIdx.x];
  float ss = v.x*v.x + v.y*v.y + v.z*v.z + v.w*v.w;
#pragma unroll
  for (int off=32; off; off>>=1) ss += __shfl_down(ss, off);
  __shared__ float ps[4];
  if ((threadIdx.x & 63) == 0) ps[threadIdx.x>>6] = ss;
  __syncthreads();
  const float tot = ps[0]+ps[1]+ps[2]+ps[3];
  const float scale = rsqrtf(tot*(1.f/1024.f) + 1e-5f);
  const float4 wv = ((const float4*)w)[threadIdx.x];
  bf16* o = out + (long)row*1024 + threadIdx.x*4;
  o[0]=f2b(v.x*scale*wv.x); o[1]=f2b(v.y*scale*wv.y);
  o[2]=f2b(v.z*scale*wv.z); o[3]=f2b(v.w*scale*wv.w);
}

// sliding-window causal conv (K=4) + bias + SiLU: thread = 8 ch x 16 steps
__global__ __launch_bounds__(256)
void k_convW(const bf16* __restrict__ xiraw, const float* __restrict__ cw,
             const float* __restrict__ cb, bf16* __restrict__ out){
  const int gid = blockIdx.x*256 + threadIdx.x;   // 8*128*256
  const int o   = gid & 255;
  const int tch = (gid >> 8) & 127;
  const int b   = gid >> 15;
  const int ch  = o << 3;
  const int t0  = tch << 4;

  float tap[4][8], bias[8];
#pragma unroll
  for (int j=0;j<8;j++){
    const float4 tv = *(const float4*)(cw + (ch+j)*4);
    tap[0][j]=tv.x; tap[1][j]=tv.y; tap[2][j]=tv.z; tap[3][j]=tv.w;
    bias[j] = cb[ch+j];
  }
  const bf16* src = xiraw + (long)b*2048*2048 + ch;
  bf16*       dstp = out  + (long)b*2048*2048 + ch;

  bf16x8 w0, w1, w2;
#pragma unroll
  for (int j=0;j<8;j++){ w0[j]=f2b(0.f); w1[j]=f2b(0.f); w2[j]=f2b(0.f); }
  if (t0 >= 3){
    w0 = *(const bf16x8*)(src + (long)(t0-3)*2048);
    w1 = *(const bf16x8*)(src + (long)(t0-2)*2048);
    w2 = *(const bf16x8*)(src + (long)(t0-1)*2048);
  }
#pragma unroll 4
  for (int t=t0; t<t0+16; ++t){
    const bf16x8 cur = *(const bf16x8*)(src + (long)t*2048);
    bf16x8 ov;
#pragma unroll
    for (int j=0;j<8;j++){
      float a = bias[j];
      a = fmaf(b2f(w0[j]),  tap[0][j], a);
      a = fmaf(b2f(w1[j]),  tap[1][j], a);
      a = fmaf(b2f(w2[j]),  tap[2][j], a);
      a = fmaf(b2f(cur[j]), tap[3][j], a);
      ov[j] = f2b(siluf_(a));
    }
    *(bf16x8*)(dstp + (long)t*2048) = ov;
    w0 = w1; w1 = w2; w2 = cur;
  }
}

// -------------------- chunked parallel scan (C=16, L=128) ------------------
#define NCHUNK 16
#define CLEN   128

__global__ __launch_bounds__(64)
void k_scanA(const bf16* __restrict__ dt, const bf16* __restrict__ xi,
             const float* __restrict__ sp, const float* __restrict__ A_log,
             float* __restrict__ F, float* __restrict__ SDT)
{
  const int tid = threadIdx.x;
  const int blk = blockIdx.x;
  const int c = blk & 15;
  const int g = (blk >> 4) & 31;
  const int b = blk >> 9;
  const int i = (g << 6) + tid;
  float Ar[16], s[16];
#pragma unroll
  for (int n=0;n<16;n++){ Ar[n] = -__expf(A_log[i*16+n]); s[n]=0.f; }
  float sdt = 0.f;
  __shared__ float Bsm[64][16];
  for (int tc=0; tc<CLEN/64; tc++){
    const int rowbase = b*2048 + c*CLEN + tc*64;
    __syncthreads();
#pragma unroll
    for (int j=0;j<16;j++){
      const int idx = (j<<6) + tid;
      Bsm[idx>>4][idx&15] = sp[(long)(rowbase + (idx>>4))*128 + 64 + (idx&15)];
    }
    __syncthreads();
    for (int tt=0; tt<64; tt+=4){
      float dtv[4], xv[4];
#pragma unroll
      for (int j2=0;j2<4;j2++){
        const long gg = (long)(rowbase+tt+j2)*2048 + i;
        dtv[j2] = b2f(dt[gg]); xv[j2] = b2f(xi[gg]);
      }
#pragma unroll
      for (int j2=0;j2<4;j2++){
        sdt += dtv[j2];
        const float dx = dtv[j2]*xv[j2];
#pragma unroll
        for (int n=0;n<16;n++)
          s[n] = fmaf(__expf(dtv[j2]*Ar[n]), s[n], dx*Bsm[tt+j2][n]);
      }
    }
  }
#pragma unroll
  for (int n=0;n<16;n++) F[((long)blk*16 + n)*64 + tid] = s[n];
  SDT[(long)blk*64 + tid] = sdt;
}

__global__ __launch_bounds__(256)
void k_scanB(float* __restrict__ F, const float* __restrict__ SDT,
             const float* __restrict__ A_log)
{
  const int t = blockIdx.x*256 + threadIdx.x;
  const int lane = t & 63;
  const int n = (t >> 6) & 15;
  const int g = (t >> 10) & 31;
  const int b = t >> 15;
  const int i = (g << 6) + lane;
  const float Ar = -__expf(A_log[i*16+n]);
  const long base = ((long)(b*32+g))*NCHUNK;
  float s0 = 0.f;
#pragma unroll
  for (int c=0;c<NCHUNK;c++){
    const long fidx = ((base + c)*16 + n)*64 + lane;
    const float f = F[fidx];
    const float p = __expf(Ar * SDT[(base + c)*64 + lane]);
    F[fidx] = s0;
    s0 = f + p*s0;
  }
}

__global__ __launch_bounds__(64)
void k_scanC(const bf16* __restrict__ dt, bf16* __restrict__ xiy,
             const float* __restrict__ sp, const float* __restrict__ A_log,
             const bf16* __restrict__ gate, const float* __restrict__ Dw,
             const float* __restrict__ S0)
{
  const int tid = threadIdx.x;
  const int blk = blockIdx.x;
  const int c = blk & 15;
  const int g = (blk >> 4) & 31;
  const int b = blk >> 9;
  const int i = (g << 6) + tid;
  const float Di = Dw[i];
  float Ar[16], s[16];
#pragma unroll
  for (int n=0;n<16;n++){
    Ar[n] = -__expf(A_log[i*16+n]);
    s[n] = S0[((long)blk*16 + n)*64 + tid];
  }
  __shared__ float BCs[64][32];
  for (int tc=0; tc<CLEN/64; tc++){
    const int rowbase = b*2048 + c*CLEN + tc*64;
    __syncthreads();
#pragma unroll
    for (int j=0;j<32;j++){
      const int idx = (j<<6) + tid;
      BCs[idx>>5][idx&31] = sp[(long)(rowbase + (idx>>5))*128 + 64 + (idx&31)];
    }
    __syncthreads();
    for (int tt=0; tt<64; tt+=4){
      float dtv[4], xv[4], gv[4];
#pragma unroll
      for (int j2=0;j2<4;j2++){
        const long gg = (long)(rowbase+tt+j2)*2048 + i;
        dtv[j2] = b2f(dt[gg]); xv[j2] = b2f(xiy[gg]); gv[j2] = b2f(gate[gg]);
      }
#pragma unroll
      for (int j2=0;j2<4;j2++){
        const float dx = dtv[j2]*xv[j2];
        float yv = 0.f;
#pragma unroll
        for (int n=0;n<16;n++){
          s[n] = fmaf(__expf(dtv[j2]*Ar[n]), s[n], dx*BCs[tt+j2][n]);
          yv = fmaf(s[n], BCs[tt+j2][16+n], yv);
        }
        xiy[(long)(rowbase+tt+j2)*2048 + i] = f2b((yv + xv[j2]*Di) * siluf_(gv[j2]));
      }
    }
  }
}

extern "C" void kernel_launch(void* const* d_in, const int* in_sizes, int n_in,
                              void* d_out, int out_size, void* d_ws, size_t ws_size,
                              hipStream_t stream)
{
  const float* x         = (const float*)d_in[0];
  const float* mixer_w   = (const float*)d_in[1];
  const float* in_proj_w = (const float*)d_in[2];
  const float* conv_w    = (const float*)d_in[3];
  const float* conv_b    = (const float*)d_in[4];
  const float* x_proj_w  = (const float*)d_in[5];
  const float* dt_proj_w = (const float*)d_in[6];
  const float* dt_proj_b = (const float*)d_in[7];
  const float* A_log     = (const float*)d_in[8];
  const float* Dv        = (const float*)d_in[9];
  const float* out_proj_w= (const float*)d_in[10];
  const float* mlp_w     = (const float*)d_in[11];
  const float* gate_w    = (const float*)d_in[12];
  const float* up_w      = (const float*)d_in[13];
  const float* down_w    = (const float*)d_in[14];
  float* outp = (float*)d_out;

  char* p = (char*)d_ws;
  auto alloc = [&](size_t n){ char* r = p; p += (n + 255) & ~(size_t)255; return (void*)r; };
  bf16* wb_in   = (bf16*)alloc((size_t)4096*1024*2);
  bf16* wb_xp   = (bf16*)alloc((size_t)128*2048*2);
  bf16* wb_dt   = (bf16*)alloc((size_t)2048*64*2);
  bf16* wb_out  = (bf16*)alloc((size_t)1024*2048*2);
  bf16* wb_gu   = (bf16*)alloc((size_t)5632*1024*2);
  bf16* wb_down = (bf16*)alloc((size_t)1024*2816*2);
  char* r1      = (char*)alloc((size_t)32<<20);
  char* r2      = (char*)alloc((size_t)64<<20);
  char* r3      = (char*)alloc((size_t)64<<20);
  char* r4      = (char*)alloc((size_t)64<<20);
  if ((size_t)(p - (char*)d_ws) > ws_size) return;

  bf16*  xb     = (bf16*)r1;
  float* sp     = (float*)r1;
  bf16*  dtr    = (bf16*)(r1 + (8<<20));
  float* Fbuf   = (float*)(r1 + (10<<20));
  float* SDT    = (float*)(r1 + (28<<20));
  bf16*  xiraw  = (bf16*)r2;
  bf16*  dtb    = (bf16*)r2;
  bf16*  gateb  = (bf16*)r3;
  bf16*  xiconv = (bf16*)r4;
  bf16*  gbuf   = (bf16*)r3;

  auto cv = [&](const float* s_, bf16* d_, int nd, int ns){
    k_convert<<<dim3((nd+255)/256), dim3(256), 0, stream>>>(s_, d_, nd, ns);
  };
  cv(in_proj_w,  wb_in,   4096*1024, 4096*1024);
  cv(x_proj_w,   wb_xp,   128*2048,  96*2048);
  cv(dt_proj_w,  wb_dt,   2048*64,   2048*64);
  cv(out_proj_w, wb_out,  1024*2048, 1024*2048);
  cv(down_w,     wb_down, 1024*2816, 1024*2816);
  k_conv_gu<<<22528, 256, 0, stream>>>(gate_w, up_w, wb_gu);

  // 1. h = rmsnorm(x)
  k_rmsnorm<<<16384, 256, 0, stream>>>(x, mixer_w, xb);
  // 2. xi / gate halves of in_proj
  gemm128s<0><<<dim3(128,16), 256, 0, stream>>>(xb, 1024, wb_in,             1024, xiraw, 2048, nullptr, 1024);
  gemm128s<0><<<dim3(128,16), 256, 0, stream>>>(xb, 1024, wb_in + 2048*1024, 1024, gateb, 2048, nullptr, 1024);
  // 3. conv + silu (sliding-window)
  k_convW<<<1024, 256, 0, stream>>>(xiraw, conv_w, conv_b, xiconv);
  // 4. sp = xiconv @ x_proj^T + fused dtr extraction
  gemm_xp<<<dim3(256,1), 256, 0, stream>>>(xiconv, wb_xp, sp, dtr, 2048);
  // 5. dt = softplus(dt_r @ dt_proj^T + b)  (K=64 -> legacy)
  gemm_bt<2><<<dim3(128,16), 256, 0, stream>>>(dtr, 64, wb_dt, 64, dtb, 2048, dt_proj_b, 64);
  // 6. chunked scan
  k_scanA<<<4096, 64, 0, stream>>>(dtb, xiconv, sp, A_log, Fbuf, SDT);
  k_scanB<<<1024, 256, 0, stream>>>(Fbuf, SDT, A_log);
  k_scanC<<<4096, 64, 0, stream>>>(dtb, xiconv, sp, A_log, gateb, Dv, Fbuf);
  // 7. x2 = x + y @ out_proj^T -> d_out
  gemm128s<3><<<dim3(128,8), 256, 0, stream>>>(xiconv, 2048, wb_out, 2048, outp, 1024, x, 2048);
  // 8. h2 = rmsnorm(x2)
  k_rmsnorm<<<16384, 256, 0, stream>>>(outp, mlp_w, xb);
  // 9. fused g = silu(h2@gate^T) * (h2@up^T)
  gemm_fused<<<dim3(128,44), 256, 0, stream>>>(xb, 1024, wb_gu, 1024, gbuf, 2816, 1024);
  // 10. d_out += g @ down^T
  gemm128s<5><<<dim3(128,8), 256, 0, stream>>>(gbuf, 2816, wb_down, 2816, outp, 1024, nullptr, 2816);
}

// Round 9
// 1228.783 us; speedup vs baseline: 1.2050x; 1.0488x over previous
//
#include <hip/hip_runtime.h>
#include <math.h>

typedef __bf16 bf16;
typedef __bf16 bf16x8 __attribute__((ext_vector_type(8)));
typedef float f32x4 __attribute__((ext_vector_type(4)));

#define DEVI static __device__ __forceinline__

DEVI float b2f(bf16 x){ return (float)x; }
DEVI bf16  f2b(float x){ return (bf16)x; }
DEVI float siluf_(float x){ return x / (1.f + __expf(-x)); }

DEVI void gload_lds16(const void* g, void* l){
  __builtin_amdgcn_global_load_lds((const __attribute__((address_space(1))) void*)g,
                                   (__attribute__((address_space(3))) void*)l, 16, 0, 0);
}

#define MFMA_  __builtin_amdgcn_mfma_f32_16x16x32_bf16

// ---------------------------------------------------------------------------
// gemm128s: C = A * W^T. m97 structure + chunk-XOR swizzle + bx-banded XCD
// remap. Split-output support: blocks with by >= bysplit write Cp2 at
// col (by-bysplit)*128 (used to write xi/gate halves of in_proj in ONE pass
// over A). Requires gridDim.x==128.
// Epilogues: 0 bf16 | 3 fp32 acc+aux[idx] | 5 C+=acc fp32
// ---------------------------------------------------------------------------
template<int EPI>
__global__ __launch_bounds__(256)
void gemm128s(const bf16* __restrict__ A, int lda,
              const bf16* __restrict__ W, int ldw,
              void* __restrict__ Cp, void* __restrict__ Cp2, int bysplit,
              int ldc, const float* __restrict__ aux, int K)
{
  __shared__ __align__(16) bf16 As[128*64];
  __shared__ __align__(16) bf16 Bs[128*64];
  const int tid  = threadIdx.x;
  const int lane = tid & 63;
  const int wid  = tid >> 6;

  const int old = blockIdx.y*128 + blockIdx.x;
  const int bx = ((old & 7) << 4) | ((old >> 3) & 15);
  const int by = old >> 7;

  const bf16* aR[4]; const bf16* bR[4]; int dst[4];
#pragma unroll
  for (int l=0;l<4;l++){
    const int ci = l*256 + tid;
    const int r  = ci >> 3;
    const int ch = (ci & 7) ^ (r & 7);
    aR[l] = A + (long)(bx*128 + r)*lda + ch*8;
    bR[l] = W + (long)(by*128 + r)*ldw + ch*8;
    dst[l] = ci*8;
  }

  f32x4 acc[4][4];
#pragma unroll
  for (int i2=0;i2<4;i2++)
#pragma unroll
    for (int j2=0;j2<4;j2++) acc[i2][j2] = {0.f,0.f,0.f,0.f};

  const int wr = (wid>>1)<<6;
  const int wc = (wid&1)<<6;
  const int fr = lane & 15;
  const int fq = lane >> 4;
  const int rs = fr & 7;
  const int jsw0 = ((fq  ) ^ rs) << 3;
  const int jsw1 = ((4|fq) ^ rs) << 3;

  for (int k0=0; k0<K; k0+=64){
    __syncthreads();
#pragma unroll
    for (int l=0;l<4;l++){
      gload_lds16(aR[l] + k0, &As[dst[l]]);
      gload_lds16(bR[l] + k0, &Bs[dst[l]]);
    }
    __syncthreads();
    bf16x8 av0[4], av1[4], bv0[4], bv1[4];
#pragma unroll
    for (int mi=0; mi<4; mi++){
      av0[mi] = *(const bf16x8*)&As[(wr + mi*16 + fr)*64 + jsw0];
      av1[mi] = *(const bf16x8*)&As[(wr + mi*16 + fr)*64 + jsw1];
    }
#pragma unroll
    for (int nj=0; nj<4; nj++){
      bv0[nj] = *(const bf16x8*)&Bs[(wc + nj*16 + fr)*64 + jsw0];
      bv1[nj] = *(const bf16x8*)&Bs[(wc + nj*16 + fr)*64 + jsw1];
    }
#pragma unroll
    for (int mi=0; mi<4; mi++)
#pragma unroll
      for (int nj=0; nj<4; nj++){
        acc[mi][nj] = MFMA_(av0[mi], bv0[nj], acc[mi][nj], 0, 0, 0);
        acc[mi][nj] = MFMA_(av1[mi], bv1[nj], acc[mi][nj], 0, 0, 0);
      }
  }

  void* Co = Cp;
  int byl = by;
  if (byl >= bysplit){ byl -= bysplit; Co = Cp2; }
  const int row0 = (bx<<7) + wr + (fq<<2);
  const int col0 = (byl<<7) + wc + fr;
#pragma unroll
  for (int mi=0; mi<4; mi++){
#pragma unroll
    for (int nj=0; nj<4; nj++){
#pragma unroll
      for (int r=0; r<4; r++){
        const int row = row0 + mi*16 + r;
        const int col = col0 + nj*16;
        const long idx = (long)row*ldc + col;
        const float v = acc[mi][nj][r];
        if constexpr (EPI==0){ ((bf16*)Co)[idx] = f2b(v); }
        else if constexpr (EPI==3){ ((float*)Co)[idx] = v + aux[idx]; }
        else { float* o = (float*)Co; o[idx] += v; }
      }
    }
  }
}

// ---------------------------------------------------------------------------
// gemm_fused: gate/up fused MLP front (wb_gu 5632x1024, 64-row interleave).
// Gate waves pass fp32 tile via XOR-swizzled LDS (conflict-free); up waves
// write silu(g)*u. Grid dim3(128, 44).
// ---------------------------------------------------------------------------
__global__ __launch_bounds__(256)
void gemm_fused(const bf16* __restrict__ A, int lda,
                const bf16* __restrict__ W, int ldw,
                bf16* __restrict__ Cp, int ldc, int K)
{
  __shared__ __align__(16) bf16 As[128*64];
  __shared__ __align__(16) bf16 Bs[128*64];
  const int tid  = threadIdx.x;
  const int lane = tid & 63;
  const int wid  = tid >> 6;

  const int old = blockIdx.y*128 + blockIdx.x;
  const int bx = ((old & 7) << 4) | ((old >> 3) & 15);
  const int by = old >> 7;

  const bf16* aR[4]; const bf16* bR[4]; int dst[4];
#pragma unroll
  for (int l=0;l<4;l++){
    const int ci = l*256 + tid;
    const int r  = ci >> 3;
    const int ch = (ci & 7) ^ (r & 7);
    aR[l] = A + (long)(bx*128 + r)*lda + ch*8;
    bR[l] = W + (long)(by*128 + r)*ldw + ch*8;
    dst[l] = ci*8;
  }

  f32x4 acc[4][4];
#pragma unroll
  for (int i2=0;i2<4;i2++)
#pragma unroll
    for (int j2=0;j2<4;j2++) acc[i2][j2] = {0.f,0.f,0.f,0.f};

  const int wr = (wid>>1)<<6;
  const int wc = (wid&1)<<6;     // 0 = gate half, 64 = up half
  const int fr = lane & 15;
  const int fq = lane >> 4;
  const int rs = fr & 7;
  const int jsw0 = ((fq  ) ^ rs) << 3;
  const int jsw1 = ((4|fq) ^ rs) << 3;

  for (int k0=0; k0<K; k0+=64){
    __syncthreads();
#pragma unroll
    for (int l=0;l<4;l++){
      gload_lds16(aR[l] + k0, &As[dst[l]]);
      gload_lds16(bR[l] + k0, &Bs[dst[l]]);
    }
    __syncthreads();
    bf16x8 av0[4], av1[4], bv0[4], bv1[4];
#pragma unroll
    for (int mi=0; mi<4; mi++){
      av0[mi] = *(const bf16x8*)&As[(wr + mi*16 + fr)*64 + jsw0];
      av1[mi] = *(const bf16x8*)&As[(wr + mi*16 + fr)*64 + jsw1];
    }
#pragma unroll
    for (int nj=0; nj<4; nj++){
      bv0[nj] = *(const bf16x8*)&Bs[(wc + nj*16 + fr)*64 + jsw0];
      bv1[nj] = *(const bf16x8*)&Bs[(wc + nj*16 + fr)*64 + jsw1];
    }
#pragma unroll
    for (int mi=0; mi<4; mi++)
#pragma unroll
      for (int nj=0; nj<4; nj++){
        acc[mi][nj] = MFMA_(av0[mi], bv0[nj], acc[mi][nj], 0, 0, 0);
        acc[mi][nj] = MFMA_(av1[mi], bv1[nj], acc[mi][nj], 0, 0, 0);
      }
  }

  // epilogue: gate tile -> LDS (fp32, XOR-swizzled), up waves combine
  __syncthreads();
  float* Gf = (wr == 0) ? (float*)As : (float*)Bs;   // 64x64 fp32 each
  if (wc == 0){
#pragma unroll
    for (int mi=0; mi<4; mi++)
#pragma unroll
      for (int nj=0; nj<4; nj++)
#pragma unroll
        for (int r=0; r<4; r++){
          const int rl = mi*16 + (fq<<2) + r;
          const int cl = nj*16 + fr;
          const int key = ((rl>>2)&3)<<4;
          Gf[rl*64 + (cl ^ key)] = acc[mi][nj][r];
        }
  }
  __syncthreads();
  if (wc == 64){
#pragma unroll
    for (int mi=0; mi<4; mi++)
#pragma unroll
      for (int nj=0; nj<4; nj++)
#pragma unroll
        for (int r=0; r<4; r++){
          const int rl = mi*16 + (fq<<2) + r;
          const int cl = nj*16 + fr;
          const int key = ((rl>>2)&3)<<4;
          const float g = Gf[rl*64 + (cl ^ key)];
          const int row = (bx<<7) + wr + rl;
          const int col = by*64 + cl;
          Cp[(long)row*ldc + col] = f2b(siluf_(g) * acc[mi][nj][r]);
        }
  }
}

// ---------------------------------------------------------------------------
// gemm_xp: x_proj, tile 64x128, writes sp fp32 + dtr bf16. Grid dim3(256,1).
// ---------------------------------------------------------------------------
__global__ __launch_bounds__(256)
void gemm_xp(const bf16* __restrict__ A, const bf16* __restrict__ W,
             float* __restrict__ sp, bf16* __restrict__ dtr, int K)
{
  __shared__ __align__(16) bf16 As[64*64];
  __shared__ __align__(16) bf16 Bs[128*64];
  const int tid  = threadIdx.x;
  const int lane = tid & 63;
  const int wid  = tid >> 6;
  const int bx = blockIdx.x;

  const bf16* aR[2]; int dstA[2];
#pragma unroll
  for (int l=0;l<2;l++){
    const int ci = l*256 + tid;
    const int r  = ci >> 3;
    const int ch = (ci & 7) ^ (r & 7);
    aR[l] = A + (long)(bx*64 + r)*2048 + ch*8;
    dstA[l] = ci*8;
  }
  const bf16* bR[4]; int dstB[4];
#pragma unroll
  for (int l=0;l<4;l++){
    const int ci = l*256 + tid;
    const int r  = ci >> 3;
    const int ch = (ci & 7) ^ (r & 7);
    bR[l] = W + (long)r*2048 + ch*8;
    dstB[l] = ci*8;
  }

  f32x4 acc[2][4];
#pragma unroll
  for (int i2=0;i2<2;i2++)
#pragma unroll
    for (int j2=0;j2<4;j2++) acc[i2][j2] = {0.f,0.f,0.f,0.f};

  const int wr = (wid>>1)<<5;
  const int wc = (wid&1)<<6;
  const int fr = lane & 15;
  const int fq = lane >> 4;
  const int rs = fr & 7;
  const int jsw0 = ((fq  ) ^ rs) << 3;
  const int jsw1 = ((4|fq) ^ rs) << 3;

  for (int k0=0; k0<K; k0+=64){
    __syncthreads();
#pragma unroll
    for (int l=0;l<2;l++) gload_lds16(aR[l] + k0, &As[dstA[l]]);
#pragma unroll
    for (int l=0;l<4;l++) gload_lds16(bR[l] + k0, &Bs[dstB[l]]);
    __syncthreads();
    bf16x8 av0[2], av1[2], bv0[4], bv1[4];
#pragma unroll
    for (int mi=0; mi<2; mi++){
      av0[mi] = *(const bf16x8*)&As[(wr + mi*16 + fr)*64 + jsw0];
      av1[mi] = *(const bf16x8*)&As[(wr + mi*16 + fr)*64 + jsw1];
    }
#pragma unroll
    for (int nj=0; nj<4; nj++){
      bv0[nj] = *(const bf16x8*)&Bs[(wc + nj*16 + fr)*64 + jsw0];
      bv1[nj] = *(const bf16x8*)&Bs[(wc + nj*16 + fr)*64 + jsw1];
    }
#pragma unroll
    for (int mi=0; mi<2; mi++)
#pragma unroll
      for (int nj=0; nj<4; nj++){
        acc[mi][nj] = MFMA_(av0[mi], bv0[nj], acc[mi][nj], 0, 0, 0);
        acc[mi][nj] = MFMA_(av1[mi], bv1[nj], acc[mi][nj], 0, 0, 0);
      }
  }

  const int row0 = (bx<<6) + wr + (fq<<2);
  const int col0 = wc + fr;
#pragma unroll
  for (int mi=0; mi<2; mi++){
#pragma unroll
    for (int nj=0; nj<4; nj++){
#pragma unroll
      for (int r=0; r<4; r++){
        const int row = row0 + mi*16 + r;
        const int col = col0 + nj*16;
        const float v = acc[mi][nj][r];
        sp[(long)row*128 + col] = v;
        if (col < 64) dtr[(long)row*64 + col] = f2b(v);
      }
    }
  }
}

// ---------------------------------------------------------------------------
// legacy 128x128 GEMM (dt_proj K=64). EPI 2: softplus(acc+aux[col])->bf16
// ---------------------------------------------------------------------------
template<int EPI>
__global__ __launch_bounds__(256)
void gemm_bt(const bf16* __restrict__ A, int lda,
             const bf16* __restrict__ W, int ldw,
             void* __restrict__ Cp, int ldc,
             const float* __restrict__ aux, int K)
{
  __shared__ __align__(16) bf16 As[128*64];
  __shared__ __align__(16) bf16 Bs[128*64];
  const int tid  = threadIdx.x;
  const int lane = tid & 63;
  const int wid  = tid >> 6;
  const int srow = tid >> 3;
  const int scol = (tid & 7) << 3;

  const bf16* Ag = A + (long)blockIdx.x*128*lda + (long)srow*lda + scol;
  const bf16* Wg = W + (long)blockIdx.y*128*ldw + (long)srow*ldw + scol;
  bf16* Asd = &As[tid*8];
  bf16* Bsd = &Bs[tid*8];

  f32x4 acc[4][4];
#pragma unroll
  for (int i2=0;i2<4;i2++)
#pragma unroll
    for (int j2=0;j2<4;j2++) acc[i2][j2] = {0.f,0.f,0.f,0.f};

  const int wr = (wid>>1)<<6;
  const int wc = (wid&1)<<6;
  const int fr = lane & 15;
  const int fq = lane >> 4;

  for (int k0=0; k0<K; k0+=64){
    __syncthreads();
#pragma unroll
    for (int is=0; is<4; is++){
      gload_lds16(Ag + (long)is*32*lda + k0, Asd + is*2048);
      gload_lds16(Wg + (long)is*32*ldw + k0, Bsd + is*2048);
    }
    __syncthreads();
#pragma unroll
    for (int kk=0; kk<2; kk++){
      bf16x8 av[4], bv[4];
#pragma unroll
      for (int mi=0; mi<4; mi++)
        av[mi] = *(const bf16x8*)&As[(wr + mi*16 + fr)*64 + kk*32 + fq*8];
#pragma unroll
      for (int nj=0; nj<4; nj++)
        bv[nj] = *(const bf16x8*)&Bs[(wc + nj*16 + fr)*64 + kk*32 + fq*8];
#pragma unroll
      for (int mi=0; mi<4; mi++)
#pragma unroll
        for (int nj=0; nj<4; nj++)
          acc[mi][nj] = MFMA_(av[mi], bv[nj], acc[mi][nj], 0, 0, 0);
    }
  }

  const int row0 = (blockIdx.x<<7) + wr + (fq<<2);
  const int col0 = (blockIdx.y<<7) + wc + fr;
#pragma unroll
  for (int mi=0; mi<4; mi++){
#pragma unroll
    for (int nj=0; nj<4; nj++){
#pragma unroll
      for (int r=0; r<4; r++){
        const int row = row0 + mi*16 + r;
        const int col = col0 + nj*16;
        const long idx = (long)row*ldc + col;
        const float v = acc[mi][nj][r];
        if constexpr (EPI==2){
          float t = v + aux[col];
          ((bf16*)Cp)[idx] = f2b(t > 20.f ? t : log1pf(__expf(t)));
        }
        else { ((bf16*)Cp)[idx] = f2b(v); }
      }
    }
  }
}

// batched fp32->bf16 weight convert: in_proj | xp(pad) | dt | out | down
__global__ void k_convert_all(const float* __restrict__ s0, const float* __restrict__ s1,
                              const float* __restrict__ s2, const float* __restrict__ s3,
                              const float* __restrict__ s4,
                              bf16* __restrict__ d0, bf16* __restrict__ d1,
                              bf16* __restrict__ d2, bf16* __restrict__ d3,
                              bf16* __restrict__ d4){
  long i = (long)blockIdx.x*256 + threadIdx.x;
  if (i < 4194304){ d0[i] = f2b(s0[i]); return; }
  i -= 4194304;
  if (i < 262144){ d1[i] = f2b(i < 196608 ? s1[i] : 0.f); return; }
  i -= 262144;
  if (i < 131072){ d2[i] = f2b(s2[i]); return; }
  i -= 131072;
  if (i < 2097152){ d3[i] = f2b(s3[i]); return; }
  i -= 2097152;
  d4[i] = f2b(s4[i]);
}

// interleaved gate/up convert: chunk c rows [0..64)=gate[c*64..], [64..128)=up
__global__ void k_conv_gu(const float* __restrict__ g, const float* __restrict__ u,
                          bf16* __restrict__ dst){
  const long i = (long)blockIdx.x*256 + threadIdx.x;   // 5632*1024
  const int row = (int)(i >> 10), col = (int)(i & 1023);
  const int chunk = row >> 7, j = row & 127;
  const float* s = (j < 64) ? (g + (long)(chunk*64 + j)*1024 + col)
                            : (u + (long)(chunk*64 + j - 64)*1024 + col);
  dst[i] = f2b(*s);
}

// RMSNorm over rows of 1024 fp32 -> bf16
__global__ __launch_bounds__(256)
void k_rmsnorm(const float* __restrict__ x, const float* __restrict__ w,
               bf16* __restrict__ out){
  const int row = blockIdx.x;
  const float4 v = ((const float4*)(x + (long)row*1024))[threadIdx.x];
  float ss = v.x*v.x + v.y*v.y + v.z*v.z + v.w*v.w;
#pragma unroll
  for (int off=32; off; off>>=1) ss += __shfl_down(ss, off);
  __shared__ float ps[4];
  if ((threadIdx.x & 63) == 0) ps[threadIdx.x>>6] = ss;
  __syncthreads();
  const float tot = ps[0]+ps[1]+ps[2]+ps[3];
  const float scale = rsqrtf(tot*(1.f/1024.f) + 1e-5f);
  const float4 wv = ((const float4*)w)[threadIdx.x];
  bf16* o = out + (long)row*1024 + threadIdx.x*4;
  o[0]=f2b(v.x*scale*wv.x); o[1]=f2b(v.y*scale*wv.y);
  o[2]=f2b(v.z*scale*wv.z); o[3]=f2b(v.w*scale*wv.w);
}

// sliding-window causal conv (K=4) + bias + SiLU: thread = 8 ch x 16 steps
__global__ __launch_bounds__(256)
void k_convW(const bf16* __restrict__ xiraw, const float* __restrict__ cw,
             const float* __restrict__ cb, bf16* __restrict__ out){
  const int gid = blockIdx.x*256 + threadIdx.x;
  const int o   = gid & 255;
  const int tch = (gid >> 8) & 127;
  const int b   = gid >> 15;
  const int ch  = o << 3;
  const int t0  = tch << 4;

  float tap[4][8], bias[8];
#pragma unroll
  for (int j=0;j<8;j++){
    const float4 tv = *(const float4*)(cw + (ch+j)*4);
    tap[0][j]=tv.x; tap[1][j]=tv.y; tap[2][j]=tv.z; tap[3][j]=tv.w;
    bias[j] = cb[ch+j];
  }
  const bf16* src = xiraw + (long)b*2048*2048 + ch;
  bf16*       dstp = out  + (long)b*2048*2048 + ch;

  bf16x8 w0, w1, w2;
#pragma unroll
  for (int j=0;j<8;j++){ w0[j]=f2b(0.f); w1[j]=f2b(0.f); w2[j]=f2b(0.f); }
  if (t0 >= 3){
    w0 = *(const bf16x8*)(src + (long)(t0-3)*2048);
    w1 = *(const bf16x8*)(src + (long)(t0-2)*2048);
    w2 = *(const bf16x8*)(src + (long)(t0-1)*2048);
  }
#pragma unroll 4
  for (int t=t0; t<t0+16; ++t){
    const bf16x8 cur = *(const bf16x8*)(src + (long)t*2048);
    bf16x8 ov;
#pragma unroll
    for (int j=0;j<8;j++){
      float a = bias[j];
      a = fmaf(b2f(w0[j]),  tap[0][j], a);
      a = fmaf(b2f(w1[j]),  tap[1][j], a);
      a = fmaf(b2f(w2[j]),  tap[2][j], a);
      a = fmaf(b2f(cur[j]), tap[3][j], a);
      ov[j] = f2b(siluf_(a));
    }
    *(bf16x8*)(dstp + (long)t*2048) = ov;
    w0 = w1; w1 = w2; w2 = cur;
  }
}

// -------------------- chunked parallel scan (C=32, L=64) -------------------
#define NCHUNK 32
#define CLEN   64

// Pass A: per-chunk local scan (s0=0). F stored bf16. blk=((b*32+g)*32+c).
__global__ __launch_bounds__(64)
void k_scanA(const bf16* __restrict__ dt, const bf16* __restrict__ xi,
             const float* __restrict__ sp, const float* __restrict__ A_log,
             bf16* __restrict__ F, float* __restrict__ SDT)
{
  const int tid = threadIdx.x;
  const int blk = blockIdx.x;
  const int c = blk & 31;
  const int g = (blk >> 5) & 31;
  const int b = blk >> 10;
  const int i = (g << 6) + tid;
  float Ar[16], s[16];
#pragma unroll
  for (int n=0;n<16;n++){ Ar[n] = -__expf(A_log[i*16+n]); s[n]=0.f; }
  float sdt = 0.f;
  __shared__ float Bsm[64][16];
  const int rowbase = b*2048 + c*CLEN;
#pragma unroll
  for (int j=0;j<16;j++){
    const int idx = (j<<6) + tid;
    Bsm[idx>>4][idx&15] = sp[(long)(rowbase + (idx>>4))*128 + 64 + (idx&15)];
  }
  __syncthreads();
  for (int tt=0; tt<CLEN; tt+=4){
    float dtv[4], xv[4];
#pragma unroll
    for (int j2=0;j2<4;j2++){
      const long gg = (long)(rowbase+tt+j2)*2048 + i;
      dtv[j2] = b2f(dt[gg]); xv[j2] = b2f(xi[gg]);
    }
#pragma unroll
    for (int j2=0;j2<4;j2++){
      sdt += dtv[j2];
      const float dx = dtv[j2]*xv[j2];
#pragma unroll
      for (int n=0;n<16;n++)
        s[n] = fmaf(__expf(dtv[j2]*Ar[n]), s[n], dx*Bsm[tt+j2][n]);
    }
  }
#pragma unroll
  for (int n=0;n<16;n++) F[((long)blk*16 + n)*64 + tid] = f2b(s[n]);
  SDT[(long)blk*64 + tid] = sdt;
}

// Pass B: sequential combine; rewrites F in place as chunk-start state S0.
__global__ __launch_bounds__(256)
void k_scanB(bf16* __restrict__ F, const float* __restrict__ SDT,
             const float* __restrict__ A_log)
{
  const int t = blockIdx.x*256 + threadIdx.x;
  const int lane = t & 63;
  const int n = (t >> 6) & 15;
  const int g = (t >> 10) & 31;
  const int b = t >> 15;
  const int i = (g << 6) + lane;
  const float Ar = -__expf(A_log[i*16+n]);
  const long base = ((long)(b*32+g))*NCHUNK;
  float s0 = 0.f;
#pragma unroll
  for (int c=0;c<NCHUNK;c++){
    const long fidx = ((base + c)*16 + n)*64 + lane;
    const float f = b2f(F[fidx]);
    const float p = __expf(Ar * SDT[(base + c)*64 + lane]);
    F[fidx] = f2b(s0);
    s0 = f + p*s0;
  }
}

// Pass C: per-chunk scan seeded with S0, fused (y+xi*D)*silu(gate) epilogue.
__global__ __launch_bounds__(64)
void k_scanC(const bf16* __restrict__ dt, bf16* __restrict__ xiy,
             const float* __restrict__ sp, const float* __restrict__ A_log,
             const bf16* __restrict__ gate, const float* __restrict__ Dw,
             const bf16* __restrict__ S0)
{
  const int tid = threadIdx.x;
  const int blk = blockIdx.x;
  const int c = blk & 31;
  const int g = (blk >> 5) & 31;
  const int b = blk >> 10;
  const int i = (g << 6) + tid;
  const float Di = Dw[i];
  float Ar[16], s[16];
#pragma unroll
  for (int n=0;n<16;n++){
    Ar[n] = -__expf(A_log[i*16+n]);
    s[n] = b2f(S0[((long)blk*16 + n)*64 + tid]);
  }
  __shared__ float BCs[64][32];
  const int rowbase = b*2048 + c*CLEN;
#pragma unroll
  for (int j=0;j<32;j++){
    const int idx = (j<<6) + tid;
    BCs[idx>>5][idx&31] = sp[(long)(rowbase + (idx>>5))*128 + 64 + (idx&31)];
  }
  __syncthreads();
  for (int tt=0; tt<CLEN; tt+=4){
    float dtv[4], xv[4], gv[4];
#pragma unroll
    for (int j2=0;j2<4;j2++){
      const long gg = (long)(rowbase+tt+j2)*2048 + i;
      dtv[j2] = b2f(dt[gg]); xv[j2] = b2f(xiy[gg]); gv[j2] = b2f(gate[gg]);
    }
#pragma unroll
    for (int j2=0;j2<4;j2++){
      const float dx = dtv[j2]*xv[j2];
      float yv = 0.f;
#pragma unroll
      for (int n=0;n<16;n++){
        s[n] = fmaf(__expf(dtv[j2]*Ar[n]), s[n], dx*BCs[tt+j2][n]);
        yv = fmaf(s[n], BCs[tt+j2][16+n], yv);
      }
      xiy[(long)(rowbase+tt+j2)*2048 + i] = f2b((yv + xv[j2]*Di) * siluf_(gv[j2]));
    }
  }
}

extern "C" void kernel_launch(void* const* d_in, const int* in_sizes, int n_in,
                              void* d_out, int out_size, void* d_ws, size_t ws_size,
                              hipStream_t stream)
{
  const float* x         = (const float*)d_in[0];
  const float* mixer_w   = (const float*)d_in[1];
  const float* in_proj_w = (const float*)d_in[2];
  const float* conv_w    = (const float*)d_in[3];
  const float* conv_b    = (const float*)d_in[4];
  const float* x_proj_w  = (const float*)d_in[5];
  const float* dt_proj_w = (const float*)d_in[6];
  const float* dt_proj_b = (const float*)d_in[7];
  const float* A_log     = (const float*)d_in[8];
  const float* Dv        = (const float*)d_in[9];
  const float* out_proj_w= (const float*)d_in[10];
  const float* mlp_w     = (const float*)d_in[11];
  const float* gate_w    = (const float*)d_in[12];
  const float* up_w      = (const float*)d_in[13];
  const float* down_w    = (const float*)d_in[14];
  float* outp = (float*)d_out;

  char* p = (char*)d_ws;
  auto alloc = [&](size_t n){ char* r = p; p += (n + 255) & ~(size_t)255; return (void*)r; };
  bf16* wb_in   = (bf16*)alloc((size_t)4096*1024*2);
  bf16* wb_xp   = (bf16*)alloc((size_t)128*2048*2);
  bf16* wb_dt   = (bf16*)alloc((size_t)2048*64*2);
  bf16* wb_out  = (bf16*)alloc((size_t)1024*2048*2);
  bf16* wb_gu   = (bf16*)alloc((size_t)5632*1024*2);
  bf16* wb_down = (bf16*)alloc((size_t)1024*2816*2);
  char* r1      = (char*)alloc((size_t)32<<20);
  char* r2      = (char*)alloc((size_t)64<<20);
  char* r3      = (char*)alloc((size_t)64<<20);
  char* r4      = (char*)alloc((size_t)64<<20);
  if ((size_t)(p - (char*)d_ws) > ws_size) return;

  bf16*  xb     = (bf16*)r1;
  float* sp     = (float*)r1;                        // 8 MB  (xb dead)
  bf16*  dtr    = (bf16*)(r1 + (8<<20));             // 2 MB
  bf16*  Fbuf   = (bf16*)(r1 + (10<<20));            // 16.8 MB (8192 blk*16*64 bf16)
  float* SDT    = (float*)(r1 + (28<<20));           // 2.1 MB
  bf16*  xiraw  = (bf16*)r2;
  bf16*  dtb    = (bf16*)r2;
  bf16*  gateb  = (bf16*)r3;
  bf16*  xiconv = (bf16*)r4;
  bf16*  gbuf   = (bf16*)r3;

  // weight converts (batched) + gate/up interleave
  k_convert_all<<<37376, 256, 0, stream>>>(in_proj_w, x_proj_w, dt_proj_w,
                                           out_proj_w, down_w,
                                           wb_in, wb_xp, wb_dt, wb_out, wb_down);
  k_conv_gu<<<22528, 256, 0, stream>>>(gate_w, up_w, wb_gu);

  // 1. h = rmsnorm(x)
  k_rmsnorm<<<16384, 256, 0, stream>>>(x, mixer_w, xb);
  // 2. in_proj: xi (by<16 -> xiraw) and gate (by>=16 -> gateb) in ONE pass
  gemm128s<0><<<dim3(128,32), 256, 0, stream>>>(xb, 1024, wb_in, 1024,
                                                xiraw, gateb, 16, 2048, nullptr, 1024);
  // 3. conv + silu (sliding-window)
  k_convW<<<1024, 256, 0, stream>>>(xiraw, conv_w, conv_b, xiconv);
  // 4. sp = xiconv @ x_proj^T + fused dtr extraction
  gemm_xp<<<dim3(256,1), 256, 0, stream>>>(xiconv, wb_xp, sp, dtr, 2048);
  // 5. dt = softplus(dt_r @ dt_proj^T + b)
  gemm_bt<2><<<dim3(128,16), 256, 0, stream>>>(dtr, 64, wb_dt, 64, dtb, 2048, dt_proj_b, 64);
  // 6. chunked scan (32 chunks of 64)
  k_scanA<<<8192, 64, 0, stream>>>(dtb, xiconv, sp, A_log, Fbuf, SDT);
  k_scanB<<<1024, 256, 0, stream>>>(Fbuf, SDT, A_log);
  k_scanC<<<8192, 64, 0, stream>>>(dtb, xiconv, sp, A_log, gateb, Dv, Fbuf);
  // 7. x2 = x + y @ out_proj^T -> d_out
  gemm128s<3><<<dim3(128,8), 256, 0, stream>>>(xiconv, 2048, wb_out, 2048,
                                               outp, nullptr, 1<<30, 1024, x, 2048);
  // 8. h2 = rmsnorm(x2)
  k_rmsnorm<<<16384, 256, 0, stream>>>(outp, mlp_w, xb);
  // 9. fused g = silu(h2@gate^T) * (h2@up^T)
  gemm_fused<<<dim3(128,44), 256, 0, stream>>>(xb, 1024, wb_gu, 1024, gbuf, 2816, 1024);
  // 10. d_out += g @ down^T
  gemm128s<5><<<dim3(128,8), 256, 0, stream>>>(gbuf, 2816, wb_down, 2816,
                                               outp, nullptr, 1<<30, 1024, nullptr, 2816);
}

// Round 10
// 989.961 us; speedup vs baseline: 1.4958x; 1.2412x over previous
//
#include <hip/hip_runtime.h>
#include <math.h>

typedef __bf16 bf16;
typedef __bf16 bf16x8 __attribute__((ext_vector_type(8)));
typedef float f32x4 __attribute__((ext_vector_type(4)));

#define DEVI static __device__ __forceinline__

DEVI float b2f(bf16 x){ return (float)x; }
DEVI bf16  f2b(float x){ return (bf16)x; }
DEVI float siluf_(float x){ return x / (1.f + __expf(-x)); }

DEVI void gload_lds16(const void* g, void* l){
  __builtin_amdgcn_global_load_lds((const __attribute__((address_space(1))) void*)g,
                                   (__attribute__((address_space(3))) void*)l, 16, 0, 0);
}

#define MFMA_  __builtin_amdgcn_mfma_f32_16x16x32_bf16

// ---------------------------------------------------------------------------
// gemm128s: C = A * W^T. m97 structure + chunk-XOR swizzle + bx-banded XCD
// remap. launch_bounds(256,3): VGPR cap ~170 (m97 regime) so the compiler can
// keep staging pointers + ds_read addresses in registers instead of
// rematerializing per iteration (r9: VALUBusy 39% at 96 VGPR).
// Split-output: blocks with by >= bysplit write Cp2 at col (by-bysplit)*128.
// Epilogues: 0 bf16 | 3 fp32 acc+aux[idx] | 5 C+=acc fp32
// ---------------------------------------------------------------------------
template<int EPI>
__global__ __launch_bounds__(256, 3)
void gemm128s(const bf16* __restrict__ A, int lda,
              const bf16* __restrict__ W, int ldw,
              void* __restrict__ Cp, void* __restrict__ Cp2, int bysplit,
              int ldc, const float* __restrict__ aux, int K)
{
  __shared__ __align__(16) bf16 As[128*64];
  __shared__ __align__(16) bf16 Bs[128*64];
  const int tid  = threadIdx.x;
  const int lane = tid & 63;
  const int wid  = tid >> 6;

  const int old = blockIdx.y*128 + blockIdx.x;
  const int bx = ((old & 7) << 4) | ((old >> 3) & 15);
  const int by = old >> 7;

  const bf16* aR[4]; const bf16* bR[4]; int dst[4];
#pragma unroll
  for (int l=0;l<4;l++){
    const int ci = l*256 + tid;
    const int r  = ci >> 3;
    const int ch = (ci & 7) ^ (r & 7);
    aR[l] = A + (long)(bx*128 + r)*lda + ch*8;
    bR[l] = W + (long)(by*128 + r)*ldw + ch*8;
    dst[l] = ci*8;
  }

  f32x4 acc[4][4];
#pragma unroll
  for (int i2=0;i2<4;i2++)
#pragma unroll
    for (int j2=0;j2<4;j2++) acc[i2][j2] = {0.f,0.f,0.f,0.f};

  const int wr = (wid>>1)<<6;
  const int wc = (wid&1)<<6;
  const int fr = lane & 15;
  const int fq = lane >> 4;
  const int rs = fr & 7;
  const int jsw0 = ((fq  ) ^ rs) << 3;
  const int jsw1 = ((4|fq) ^ rs) << 3;

  for (int k0=0; k0<K; k0+=64){
    __syncthreads();
#pragma unroll
    for (int l=0;l<4;l++){
      gload_lds16(aR[l] + k0, &As[dst[l]]);
      gload_lds16(bR[l] + k0, &Bs[dst[l]]);
    }
    __syncthreads();
    bf16x8 av0[4], av1[4], bv0[4], bv1[4];
#pragma unroll
    for (int mi=0; mi<4; mi++){
      av0[mi] = *(const bf16x8*)&As[(wr + mi*16 + fr)*64 + jsw0];
      av1[mi] = *(const bf16x8*)&As[(wr + mi*16 + fr)*64 + jsw1];
    }
#pragma unroll
    for (int nj=0; nj<4; nj++){
      bv0[nj] = *(const bf16x8*)&Bs[(wc + nj*16 + fr)*64 + jsw0];
      bv1[nj] = *(const bf16x8*)&Bs[(wc + nj*16 + fr)*64 + jsw1];
    }
#pragma unroll
    for (int mi=0; mi<4; mi++)
#pragma unroll
      for (int nj=0; nj<4; nj++){
        acc[mi][nj] = MFMA_(av0[mi], bv0[nj], acc[mi][nj], 0, 0, 0);
        acc[mi][nj] = MFMA_(av1[mi], bv1[nj], acc[mi][nj], 0, 0, 0);
      }
  }

  void* Co = Cp;
  int byl = by;
  if (byl >= bysplit){ byl -= bysplit; Co = Cp2; }
  const int row0 = (bx<<7) + wr + (fq<<2);
  const int col0 = (byl<<7) + wc + fr;
#pragma unroll
  for (int mi=0; mi<4; mi++){
#pragma unroll
    for (int nj=0; nj<4; nj++){
#pragma unroll
      for (int r=0; r<4; r++){
        const int row = row0 + mi*16 + r;
        const int col = col0 + nj*16;
        const long idx = (long)row*ldc + col;
        const float v = acc[mi][nj][r];
        if constexpr (EPI==0){ ((bf16*)Co)[idx] = f2b(v); }
        else if constexpr (EPI==3){ ((float*)Co)[idx] = v + aux[idx]; }
        else { float* o = (float*)Co; o[idx] += v; }
      }
    }
  }
}

// ---------------------------------------------------------------------------
// gemm_fused: gate/up fused MLP front (wb_gu 5632x1024, 64-row interleave).
// Gate waves pass fp32 tile via XOR-swizzled LDS; up waves write silu(g)*u.
// Grid dim3(128, 44).
// ---------------------------------------------------------------------------
__global__ __launch_bounds__(256, 3)
void gemm_fused(const bf16* __restrict__ A, int lda,
                const bf16* __restrict__ W, int ldw,
                bf16* __restrict__ Cp, int ldc, int K)
{
  __shared__ __align__(16) bf16 As[128*64];
  __shared__ __align__(16) bf16 Bs[128*64];
  const int tid  = threadIdx.x;
  const int lane = tid & 63;
  const int wid  = tid >> 6;

  const int old = blockIdx.y*128 + blockIdx.x;
  const int bx = ((old & 7) << 4) | ((old >> 3) & 15);
  const int by = old >> 7;

  const bf16* aR[4]; const bf16* bR[4]; int dst[4];
#pragma unroll
  for (int l=0;l<4;l++){
    const int ci = l*256 + tid;
    const int r  = ci >> 3;
    const int ch = (ci & 7) ^ (r & 7);
    aR[l] = A + (long)(bx*128 + r)*lda + ch*8;
    bR[l] = W + (long)(by*128 + r)*ldw + ch*8;
    dst[l] = ci*8;
  }

  f32x4 acc[4][4];
#pragma unroll
  for (int i2=0;i2<4;i2++)
#pragma unroll
    for (int j2=0;j2<4;j2++) acc[i2][j2] = {0.f,0.f,0.f,0.f};

  const int wr = (wid>>1)<<6;
  const int wc = (wid&1)<<6;     // 0 = gate half, 64 = up half
  const int fr = lane & 15;
  const int fq = lane >> 4;
  const int rs = fr & 7;
  const int jsw0 = ((fq  ) ^ rs) << 3;
  const int jsw1 = ((4|fq) ^ rs) << 3;

  for (int k0=0; k0<K; k0+=64){
    __syncthreads();
#pragma unroll
    for (int l=0;l<4;l++){
      gload_lds16(aR[l] + k0, &As[dst[l]]);
      gload_lds16(bR[l] + k0, &Bs[dst[l]]);
    }
    __syncthreads();
    bf16x8 av0[4], av1[4], bv0[4], bv1[4];
#pragma unroll
    for (int mi=0; mi<4; mi++){
      av0[mi] = *(const bf16x8*)&As[(wr + mi*16 + fr)*64 + jsw0];
      av1[mi] = *(const bf16x8*)&As[(wr + mi*16 + fr)*64 + jsw1];
    }
#pragma unroll
    for (int nj=0; nj<4; nj++){
      bv0[nj] = *(const bf16x8*)&Bs[(wc + nj*16 + fr)*64 + jsw0];
      bv1[nj] = *(const bf16x8*)&Bs[(wc + nj*16 + fr)*64 + jsw1];
    }
#pragma unroll
    for (int mi=0; mi<4; mi++)
#pragma unroll
      for (int nj=0; nj<4; nj++){
        acc[mi][nj] = MFMA_(av0[mi], bv0[nj], acc[mi][nj], 0, 0, 0);
        acc[mi][nj] = MFMA_(av1[mi], bv1[nj], acc[mi][nj], 0, 0, 0);
      }
  }

  // epilogue: gate tile -> LDS (fp32, XOR-swizzled), up waves combine
  __syncthreads();
  float* Gf = (wr == 0) ? (float*)As : (float*)Bs;   // 64x64 fp32 each
  if (wc == 0){
#pragma unroll
    for (int mi=0; mi<4; mi++)
#pragma unroll
      for (int nj=0; nj<4; nj++)
#pragma unroll
        for (int r=0; r<4; r++){
          const int rl = mi*16 + (fq<<2) + r;
          const int cl = nj*16 + fr;
          const int key = ((rl>>2)&3)<<4;
          Gf[rl*64 + (cl ^ key)] = acc[mi][nj][r];
        }
  }
  __syncthreads();
  if (wc == 64){
#pragma unroll
    for (int mi=0; mi<4; mi++)
#pragma unroll
      for (int nj=0; nj<4; nj++)
#pragma unroll
        for (int r=0; r<4; r++){
          const int rl = mi*16 + (fq<<2) + r;
          const int cl = nj*16 + fr;
          const int key = ((rl>>2)&3)<<4;
          const float g = Gf[rl*64 + (cl ^ key)];
          const int row = (bx<<7) + wr + rl;
          const int col = by*64 + cl;
          Cp[(long)row*ldc + col] = f2b(siluf_(g) * acc[mi][nj][r]);
        }
  }
}

// ---------------------------------------------------------------------------
// gemm_xp: x_proj, tile 64x128, writes sp fp32 + dtr bf16. Grid dim3(256,1).
// ---------------------------------------------------------------------------
__global__ __launch_bounds__(256, 3)
void gemm_xp(const bf16* __restrict__ A, const bf16* __restrict__ W,
             float* __restrict__ sp, bf16* __restrict__ dtr, int K)
{
  __shared__ __align__(16) bf16 As[64*64];
  __shared__ __align__(16) bf16 Bs[128*64];
  const int tid  = threadIdx.x;
  const int lane = tid & 63;
  const int wid  = tid >> 6;
  const int bx = blockIdx.x;

  const bf16* aR[2]; int dstA[2];
#pragma unroll
  for (int l=0;l<2;l++){
    const int ci = l*256 + tid;
    const int r  = ci >> 3;
    const int ch = (ci & 7) ^ (r & 7);
    aR[l] = A + (long)(bx*64 + r)*2048 + ch*8;
    dstA[l] = ci*8;
  }
  const bf16* bR[4]; int dstB[4];
#pragma unroll
  for (int l=0;l<4;l++){
    const int ci = l*256 + tid;
    const int r  = ci >> 3;
    const int ch = (ci & 7) ^ (r & 7);
    bR[l] = W + (long)r*2048 + ch*8;
    dstB[l] = ci*8;
  }

  f32x4 acc[2][4];
#pragma unroll
  for (int i2=0;i2<2;i2++)
#pragma unroll
    for (int j2=0;j2<4;j2++) acc[i2][j2] = {0.f,0.f,0.f,0.f};

  const int wr = (wid>>1)<<5;
  const int wc = (wid&1)<<6;
  const int fr = lane & 15;
  const int fq = lane >> 4;
  const int rs = fr & 7;
  const int jsw0 = ((fq  ) ^ rs) << 3;
  const int jsw1 = ((4|fq) ^ rs) << 3;

  for (int k0=0; k0<K; k0+=64){
    __syncthreads();
#pragma unroll
    for (int l=0;l<2;l++) gload_lds16(aR[l] + k0, &As[dstA[l]]);
#pragma unroll
    for (int l=0;l<4;l++) gload_lds16(bR[l] + k0, &Bs[dstB[l]]);
    __syncthreads();
    bf16x8 av0[2], av1[2], bv0[4], bv1[4];
#pragma unroll
    for (int mi=0; mi<2; mi++){
      av0[mi] = *(const bf16x8*)&As[(wr + mi*16 + fr)*64 + jsw0];
      av1[mi] = *(const bf16x8*)&As[(wr + mi*16 + fr)*64 + jsw1];
    }
#pragma unroll
    for (int nj=0; nj<4; nj++){
      bv0[nj] = *(const bf16x8*)&Bs[(wc + nj*16 + fr)*64 + jsw0];
      bv1[nj] = *(const bf16x8*)&Bs[(wc + nj*16 + fr)*64 + jsw1];
    }
#pragma unroll
    for (int mi=0; mi<2; mi++)
#pragma unroll
      for (int nj=0; nj<4; nj++){
        acc[mi][nj] = MFMA_(av0[mi], bv0[nj], acc[mi][nj], 0, 0, 0);
        acc[mi][nj] = MFMA_(av1[mi], bv1[nj], acc[mi][nj], 0, 0, 0);
      }
  }

  const int row0 = (bx<<6) + wr + (fq<<2);
  const int col0 = wc + fr;
#pragma unroll
  for (int mi=0; mi<2; mi++){
#pragma unroll
    for (int nj=0; nj<4; nj++){
#pragma unroll
      for (int r=0; r<4; r++){
        const int row = row0 + mi*16 + r;
        const int col = col0 + nj*16;
        const float v = acc[mi][nj][r];
        sp[(long)row*128 + col] = v;
        if (col < 64) dtr[(long)row*64 + col] = f2b(v);
      }
    }
  }
}

// ---------------------------------------------------------------------------
// legacy 128x128 GEMM (dt_proj K=64). EPI 2: softplus(acc+aux[col])->bf16
// ---------------------------------------------------------------------------
template<int EPI>
__global__ __launch_bounds__(256, 3)
void gemm_bt(const bf16* __restrict__ A, int lda,
             const bf16* __restrict__ W, int ldw,
             void* __restrict__ Cp, int ldc,
             const float* __restrict__ aux, int K)
{
  __shared__ __align__(16) bf16 As[128*64];
  __shared__ __align__(16) bf16 Bs[128*64];
  const int tid  = threadIdx.x;
  const int lane = tid & 63;
  const int wid  = tid >> 6;
  const int srow = tid >> 3;
  const int scol = (tid & 7) << 3;

  const bf16* Ag = A + (long)blockIdx.x*128*lda + (long)srow*lda + scol;
  const bf16* Wg = W + (long)blockIdx.y*128*ldw + (long)srow*ldw + scol;
  bf16* Asd = &As[tid*8];
  bf16* Bsd = &Bs[tid*8];

  f32x4 acc[4][4];
#pragma unroll
  for (int i2=0;i2<4;i2++)
#pragma unroll
    for (int j2=0;j2<4;j2++) acc[i2][j2] = {0.f,0.f,0.f,0.f};

  const int wr = (wid>>1)<<6;
  const int wc = (wid&1)<<6;
  const int fr = lane & 15;
  const int fq = lane >> 4;

  for (int k0=0; k0<K; k0+=64){
    __syncthreads();
#pragma unroll
    for (int is=0; is<4; is++){
      gload_lds16(Ag + (long)is*32*lda + k0, Asd + is*2048);
      gload_lds16(Wg + (long)is*32*ldw + k0, Bsd + is*2048);
    }
    __syncthreads();
#pragma unroll
    for (int kk=0; kk<2; kk++){
      bf16x8 av[4], bv[4];
#pragma unroll
      for (int mi=0; mi<4; mi++)
        av[mi] = *(const bf16x8*)&As[(wr + mi*16 + fr)*64 + kk*32 + fq*8];
#pragma unroll
      for (int nj=0; nj<4; nj++)
        bv[nj] = *(const bf16x8*)&Bs[(wc + nj*16 + fr)*64 + kk*32 + fq*8];
#pragma unroll
      for (int mi=0; mi<4; mi++)
#pragma unroll
        for (int nj=0; nj<4; nj++)
          acc[mi][nj] = MFMA_(av[mi], bv[nj], acc[mi][nj], 0, 0, 0);
    }
  }

  const int row0 = (blockIdx.x<<7) + wr + (fq<<2);
  const int col0 = (blockIdx.y<<7) + wc + fr;
#pragma unroll
  for (int mi=0; mi<4; mi++){
#pragma unroll
    for (int nj=0; nj<4; nj++){
#pragma unroll
      for (int r=0; r<4; r++){
        const int row = row0 + mi*16 + r;
        const int col = col0 + nj*16;
        const long idx = (long)row*ldc + col;
        const float v = acc[mi][nj][r];
        if constexpr (EPI==2){
          float t = v + aux[col];
          ((bf16*)Cp)[idx] = f2b(t > 20.f ? t : log1pf(__expf(t)));
        }
        else { ((bf16*)Cp)[idx] = f2b(v); }
      }
    }
  }
}

// batched fp32->bf16 weight convert: in_proj | xp(pad) | dt | out | down
__global__ void k_convert_all(const float* __restrict__ s0, const float* __restrict__ s1,
                              const float* __restrict__ s2, const float* __restrict__ s3,
                              const float* __restrict__ s4,
                              bf16* __restrict__ d0, bf16* __restrict__ d1,
                              bf16* __restrict__ d2, bf16* __restrict__ d3,
                              bf16* __restrict__ d4){
  long i = (long)blockIdx.x*256 + threadIdx.x;
  if (i < 4194304){ d0[i] = f2b(s0[i]); return; }
  i -= 4194304;
  if (i < 262144){ d1[i] = f2b(i < 196608 ? s1[i] : 0.f); return; }
  i -= 262144;
  if (i < 131072){ d2[i] = f2b(s2[i]); return; }
  i -= 131072;
  if (i < 2097152){ d3[i] = f2b(s3[i]); return; }
  i -= 2097152;
  d4[i] = f2b(s4[i]);
}

// interleaved gate/up convert: chunk c rows [0..64)=gate[c*64..], [64..128)=up
__global__ void k_conv_gu(const float* __restrict__ g, const float* __restrict__ u,
                          bf16* __restrict__ dst){
  const long i = (long)blockIdx.x*256 + threadIdx.x;   // 5632*1024
  const int row = (int)(i >> 10), col = (int)(i & 1023);
  const int chunk = row >> 7, j = row & 127;
  const float* s = (j < 64) ? (g + (long)(chunk*64 + j)*1024 + col)
                            : (u + (long)(chunk*64 + j - 64)*1024 + col);
  dst[i] = f2b(*s);
}

// RMSNorm over rows of 1024 fp32 -> bf16
__global__ __launch_bounds__(256)
void k_rmsnorm(const float* __restrict__ x, const float* __restrict__ w,
               bf16* __restrict__ out){
  const int row = blockIdx.x;
  const float4 v = ((const float4*)(x + (long)row*1024))[threadIdx.x];
  float ss = v.x*v.x + v.y*v.y + v.z*v.z + v.w*v.w;
#pragma unroll
  for (int off=32; off; off>>=1) ss += __shfl_down(ss, off);
  __shared__ float ps[4];
  if ((threadIdx.x & 63) == 0) ps[threadIdx.x>>6] = ss;
  __syncthreads();
  const float tot = ps[0]+ps[1]+ps[2]+ps[3];
  const float scale = rsqrtf(tot*(1.f/1024.f) + 1e-5f);
  const float4 wv = ((const float4*)w)[threadIdx.x];
  bf16* o = out + (long)row*1024 + threadIdx.x*4;
  o[0]=f2b(v.x*scale*wv.x); o[1]=f2b(v.y*scale*wv.y);
  o[2]=f2b(v.z*scale*wv.z); o[3]=f2b(v.w*scale*wv.w);
}

// sliding-window causal conv (K=4) + bias + SiLU: thread = 8 ch x 16 steps
__global__ __launch_bounds__(256)
void k_convW(const bf16* __restrict__ xiraw, const float* __restrict__ cw,
             const float* __restrict__ cb, bf16* __restrict__ out){
  const int gid = blockIdx.x*256 + threadIdx.x;
  const int o   = gid & 255;
  const int tch = (gid >> 8) & 127;
  const int b   = gid >> 15;
  const int ch  = o << 3;
  const int t0  = tch << 4;

  float tap[4][8], bias[8];
#pragma unroll
  for (int j=0;j<8;j++){
    const float4 tv = *(const float4*)(cw + (ch+j)*4);
    tap[0][j]=tv.x; tap[1][j]=tv.y; tap[2][j]=tv.z; tap[3][j]=tv.w;
    bias[j] = cb[ch+j];
  }
  const bf16* src = xiraw + (long)b*2048*2048 + ch;
  bf16*       dstp = out  + (long)b*2048*2048 + ch;

  bf16x8 w0, w1, w2;
#pragma unroll
  for (int j=0;j<8;j++){ w0[j]=f2b(0.f); w1[j]=f2b(0.f); w2[j]=f2b(0.f); }
  if (t0 >= 3){
    w0 = *(const bf16x8*)(src + (long)(t0-3)*2048);
    w1 = *(const bf16x8*)(src + (long)(t0-2)*2048);
    w2 = *(const bf16x8*)(src + (long)(t0-1)*2048);
  }
#pragma unroll 4
  for (int t=t0; t<t0+16; ++t){
    const bf16x8 cur = *(const bf16x8*)(src + (long)t*2048);
    bf16x8 ov;
#pragma unroll
    for (int j=0;j<8;j++){
      float a = bias[j];
      a = fmaf(b2f(w0[j]),  tap[0][j], a);
      a = fmaf(b2f(w1[j]),  tap[1][j], a);
      a = fmaf(b2f(w2[j]),  tap[2][j], a);
      a = fmaf(b2f(cur[j]), tap[3][j], a);
      ov[j] = f2b(siluf_(a));
    }
    *(bf16x8*)(dstp + (long)t*2048) = ov;
    w0 = w1; w1 = w2; w2 = cur;
  }
}

// -------------------- chunked parallel scan (C=32, L=64) -------------------
#define NCHUNK 32
#define CLEN   64

// Pass A: per-chunk local scan (s0=0). F stored bf16. blk=((b*32+g)*32+c).
__global__ __launch_bounds__(64)
void k_scanA(const bf16* __restrict__ dt, const bf16* __restrict__ xi,
             const float* __restrict__ sp, const float* __restrict__ A_log,
             bf16* __restrict__ F, float* __restrict__ SDT)
{
  const int tid = threadIdx.x;
  const int blk = blockIdx.x;
  const int c = blk & 31;
  const int g = (blk >> 5) & 31;
  const int b = blk >> 10;
  const int i = (g << 6) + tid;
  float Ar[16], s[16];
#pragma unroll
  for (int n=0;n<16;n++){ Ar[n] = -__expf(A_log[i*16+n]); s[n]=0.f; }
  float sdt = 0.f;
  __shared__ float Bsm[64][16];
  const int rowbase = b*2048 + c*CLEN;
#pragma unroll
  for (int j=0;j<16;j++){
    const int idx = (j<<6) + tid;
    Bsm[idx>>4][idx&15] = sp[(long)(rowbase + (idx>>4))*128 + 64 + (idx&15)];
  }
  __syncthreads();
  for (int tt=0; tt<CLEN; tt+=4){
    float dtv[4], xv[4];
#pragma unroll
    for (int j2=0;j2<4;j2++){
      const long gg = (long)(rowbase+tt+j2)*2048 + i;
      dtv[j2] = b2f(dt[gg]); xv[j2] = b2f(xi[gg]);
    }
#pragma unroll
    for (int j2=0;j2<4;j2++){
      sdt += dtv[j2];
      const float dx = dtv[j2]*xv[j2];
#pragma unroll
      for (int n=0;n<16;n++)
        s[n] = fmaf(__expf(dtv[j2]*Ar[n]), s[n], dx*Bsm[tt+j2][n]);
    }
  }
#pragma unroll
  for (int n=0;n<16;n++) F[((long)blk*16 + n)*64 + tid] = f2b(s[n]);
  SDT[(long)blk*64 + tid] = sdt;
}

// Pass B: sequential combine; rewrites F in place as chunk-start state S0.
__global__ __launch_bounds__(256)
void k_scanB(bf16* __restrict__ F, const float* __restrict__ SDT,
             const float* __restrict__ A_log)
{
  const int t = blockIdx.x*256 + threadIdx.x;
  const int lane = t & 63;
  const int n = (t >> 6) & 15;
  const int g = (t >> 10) & 31;
  const int b = t >> 15;
  const int i = (g << 6) + lane;
  const float Ar = -__expf(A_log[i*16+n]);
  const long base = ((long)(b*32+g))*NCHUNK;
  float s0 = 0.f;
#pragma unroll
  for (int c=0;c<NCHUNK;c++){
    const long fidx = ((base + c)*16 + n)*64 + lane;
    const float f = b2f(F[fidx]);
    const float p = __expf(Ar * SDT[(base + c)*64 + lane]);
    F[fidx] = f2b(s0);
    s0 = f + p*s0;
  }
}

// Pass C: per-chunk scan seeded with S0, fused (y+xi*D)*silu(gate) epilogue.
__global__ __launch_bounds__(64)
void k_scanC(const bf16* __restrict__ dt, bf16* __restrict__ xiy,
             const float* __restrict__ sp, const float* __restrict__ A_log,
             const bf16* __restrict__ gate, const float* __restrict__ Dw,
             const bf16* __restrict__ S0)
{
  const int tid = threadIdx.x;
  const int blk = blockIdx.x;
  const int c = blk & 31;
  const int g = (blk >> 5) & 31;
  const int b = blk >> 10;
  const int i = (g << 6) + tid;
  const float Di = Dw[i];
  float Ar[16], s[16];
#pragma unroll
  for (int n=0;n<16;n++){
    Ar[n] = -__expf(A_log[i*16+n]);
    s[n] = b2f(S0[((long)blk*16 + n)*64 + tid]);
  }
  __shared__ float BCs[64][32];
  const int rowbase = b*2048 + c*CLEN;
#pragma unroll
  for (int j=0;j<32;j++){
    const int idx = (j<<6) + tid;
    BCs[idx>>5][idx&31] = sp[(long)(rowbase + (idx>>5))*128 + 64 + (idx&31)];
  }
  __syncthreads();
  for (int tt=0; tt<CLEN; tt+=4){
    float dtv[4], xv[4], gv[4];
#pragma unroll
    for (int j2=0;j2<4;j2++){
      const long gg = (long)(rowbase+tt+j2)*2048 + i;
      dtv[j2] = b2f(dt[gg]); xv[j2] = b2f(xiy[gg]); gv[j2] = b2f(gate[gg]);
    }
#pragma unroll
    for (int j2=0;j2<4;j2++){
      const float dx = dtv[j2]*xv[j2];
      float yv = 0.f;
#pragma unroll
      for (int n=0;n<16;n++){
        s[n] = fmaf(__expf(dtv[j2]*Ar[n]), s[n], dx*BCs[tt+j2][n]);
        yv = fmaf(s[n], BCs[tt+j2][16+n], yv);
      }
      xiy[(long)(rowbase+tt+j2)*2048 + i] = f2b((yv + xv[j2]*Di) * siluf_(gv[j2]));
    }
  }
}

extern "C" void kernel_launch(void* const* d_in, const int* in_sizes, int n_in,
                              void* d_out, int out_size, void* d_ws, size_t ws_size,
                              hipStream_t stream)
{
  const float* x         = (const float*)d_in[0];
  const float* mixer_w   = (const float*)d_in[1];
  const float* in_proj_w = (const float*)d_in[2];
  const float* conv_w    = (const float*)d_in[3];
  const float* conv_b    = (const float*)d_in[4];
  const float* x_proj_w  = (const float*)d_in[5];
  const float* dt_proj_w = (const float*)d_in[6];
  const float* dt_proj_b = (const float*)d_in[7];
  const float* A_log     = (const float*)d_in[8];
  const float* Dv        = (const float*)d_in[9];
  const float* out_proj_w= (const float*)d_in[10];
  const float* mlp_w     = (const float*)d_in[11];
  const float* gate_w    = (const float*)d_in[12];
  const float* up_w      = (const float*)d_in[13];
  const float* down_w    = (const float*)d_in[14];
  float* outp = (float*)d_out;

  char* p = (char*)d_ws;
  auto alloc = [&](size_t n){ char* r = p; p += (n + 255) & ~(size_t)255; return (void*)r; };
  bf16* wb_in   = (bf16*)alloc((size_t)4096*1024*2);
  bf16* wb_xp   = (bf16*)alloc((size_t)128*2048*2);
  bf16* wb_dt   = (bf16*)alloc((size_t)2048*64*2);
  bf16* wb_out  = (bf16*)alloc((size_t)1024*2048*2);
  bf16* wb_gu   = (bf16*)alloc((size_t)5632*1024*2);
  bf16* wb_down = (bf16*)alloc((size_t)1024*2816*2);
  char* r1      = (char*)alloc((size_t)32<<20);
  char* r2      = (char*)alloc((size_t)64<<20);
  char* r3      = (char*)alloc((size_t)64<<20);
  char* r4      = (char*)alloc((size_t)64<<20);
  if ((size_t)(p - (char*)d_ws) > ws_size) return;

  bf16*  xb     = (bf16*)r1;
  float* sp     = (float*)r1;                        // 8 MB  (xb dead)
  bf16*  dtr    = (bf16*)(r1 + (8<<20));             // 2 MB
  bf16*  Fbuf   = (bf16*)(r1 + (10<<20));            // 16.8 MB
  float* SDT    = (float*)(r1 + (28<<20));           // 2.1 MB
  bf16*  xiraw  = (bf16*)r2;
  bf16*  dtb    = (bf16*)r2;
  bf16*  gateb  = (bf16*)r3;
  bf16*  xiconv = (bf16*)r4;
  bf16*  gbuf   = (bf16*)r3;

  // weight converts (batched) + gate/up interleave
  k_convert_all<<<37376, 256, 0, stream>>>(in_proj_w, x_proj_w, dt_proj_w,
                                           out_proj_w, down_w,
                                           wb_in, wb_xp, wb_dt, wb_out, wb_down);
  k_conv_gu<<<22528, 256, 0, stream>>>(gate_w, up_w, wb_gu);

  // 1. h = rmsnorm(x)
  k_rmsnorm<<<16384, 256, 0, stream>>>(x, mixer_w, xb);
  // 2. in_proj: xi (by<16 -> xiraw) and gate (by>=16 -> gateb) in ONE pass
  gemm128s<0><<<dim3(128,32), 256, 0, stream>>>(xb, 1024, wb_in, 1024,
                                                xiraw, gateb, 16, 2048, nullptr, 1024);
  // 3. conv + silu (sliding-window)
  k_convW<<<1024, 256, 0, stream>>>(xiraw, conv_w, conv_b, xiconv);
  // 4. sp = xiconv @ x_proj^T + fused dtr extraction
  gemm_xp<<<dim3(256,1), 256, 0, stream>>>(xiconv, wb_xp, sp, dtr, 2048);
  // 5. dt = softplus(dt_r @ dt_proj^T + b)
  gemm_bt<2><<<dim3(128,16), 256, 0, stream>>>(dtr, 64, wb_dt, 64, dtb, 2048, dt_proj_b, 64);
  // 6. chunked scan (32 chunks of 64)
  k_scanA<<<8192, 64, 0, stream>>>(dtb, xiconv, sp, A_log, Fbuf, SDT);
  k_scanB<<<1024, 256, 0, stream>>>(Fbuf, SDT, A_log);
  k_scanC<<<8192, 64, 0, stream>>>(dtb, xiconv, sp, A_log, gateb, Dv, Fbuf);
  // 7. x2 = x + y @ out_proj^T -> d_out
  gemm128s<3><<<dim3(128,8), 256, 0, stream>>>(xiconv, 2048, wb_out, 2048,
                                               outp, nullptr, 1<<30, 1024, x, 2048);
  // 8. h2 = rmsnorm(x2)
  k_rmsnorm<<<16384, 256, 0, stream>>>(outp, mlp_w, xb);
  // 9. fused g = silu(h2@gate^T) * (h2@up^T)
  gemm_fused<<<dim3(128,44), 256, 0, stream>>>(xb, 1024, wb_gu, 1024, gbuf, 2816, 1024);
  // 10. d_out += g @ down^T
  gemm128s<5><<<dim3(128,8), 256, 0, stream>>>(gbuf, 2816, wb_down, 2816,
                                               outp, nullptr, 1<<30, 1024, nullptr, 2816);
}